// Round 7
// baseline (482.459 us; speedup 1.0000x reference)
//
#include <hip/hip_runtime.h>
#include <math.h>

// ---------------------------------------------------------------------------
// SophisticatedBioInspiredModel — bf16 MFMA (32x32x16), 256^2 8-phase GEMMs.
//
// Spiking attention is data-independent: 100 distinct tokens, each bumped once
// from decayed-zero -> v=1.0 < 1.2 -> no spikes -> counts==0 -> top_k(zeros,20)
// = indices 0..19 -> gains double cols 0..19 of context.
//
// GEMM: C = A(MxK,bf16) * Bt(NxK,bf16)^T. 256x256 tile, BK=64, 8 waves (2Mx4N),
// 128 KiB LDS double-buffer, 8-phase schedule (1 barrier/phase), counted
// vmcnt(4) at P4/P8 only, chunk^(row&7) swizzle, setprio, XCD swizzle.
// v_mfma_f32_32x32x16_bf16: 4060 FLOP/cy/CU ceiling vs 3378 for 16x16x32.
// C/D: col=lane&31, row=(reg&3)+8*(reg>>2)+4*(lane>>5)  [m74/m101 verified].
// ---------------------------------------------------------------------------

typedef unsigned short u16;
typedef __attribute__((ext_vector_type(8))) short bfrag8;
typedef __attribute__((ext_vector_type(4))) float facc4;
typedef __attribute__((ext_vector_type(16))) float facc16;

__device__ __forceinline__ u16 f2bf(float f) {
  union { float f; unsigned u; } c; c.f = f;
  unsigned u = c.u;
  return (u16)((u + 0x7fffu + ((u >> 16) & 1u)) >> 16);
}
__device__ __forceinline__ float bf2f(u16 h) {
  union { unsigned u; float f; } c; c.u = ((unsigned)h) << 16;
  return c.f;
}
__device__ __forceinline__ void gload16(const void* g, void* lds) {
  __builtin_amdgcn_global_load_lds(
      (const __attribute__((address_space(1))) unsigned*)g,
      (__attribute__((address_space(3))) unsigned*)lds, 16, 0, 0);
}

#define BARX() do { __builtin_amdgcn_sched_barrier(0); \
  __builtin_amdgcn_s_barrier(); __builtin_amdgcn_sched_barrier(0); } while (0)
#define VMW4() do { asm volatile("s_waitcnt vmcnt(4)" ::: "memory"); \
  __builtin_amdgcn_sched_barrier(0); } while (0)

// A sub-tile: 2 row-blocks of 32 x K=64. dst[2][4]
#define RDA32(dst, mbase, dbuf) do { \
  char* _b = smem + (dbuf) * 65536; \
  _Pragma("unroll") for (int mm = 0; mm < 2; ++mm) { \
    int _row = wr * 128 + ((mbase) + mm) * 32 + l31; \
    _Pragma("unroll") for (int kb = 0; kb < 4; ++kb) \
      dst[mm][kb] = *(const bfrag8*)(_b + _row * 128 + \
                                     (((kb * 2 + lh) ^ (_row & 7)) << 4)); \
  } } while (0)

// B sub-tile: 1 col-block of 32 x K=64. dst[4]
#define RDB32(dst, nb, dbuf) do { \
  char* _b = smem + (dbuf) * 65536 + 32768; \
  int _row = wc * 64 + (nb) * 32 + l31; \
  _Pragma("unroll") for (int kb = 0; kb < 4; ++kb) \
    dst[kb] = *(const bfrag8*)(_b + _row * 128 + \
                               (((kb * 2 + lh) ^ (_row & 7)) << 4)); \
} while (0)

// 8 x mfma_32x32x16: 2 m-blocks x 1 n-block x 4 k; interleave the 2 acc chains
#define MF32(a, b, mo, nb) do { \
  __builtin_amdgcn_s_setprio(1); \
  _Pragma("unroll") for (int kb = 0; kb < 4; ++kb) \
  _Pragma("unroll") for (int mm = 0; mm < 2; ++mm) \
    acc[(mo) + mm][nb] = __builtin_amdgcn_mfma_f32_32x32x16_bf16( \
        a[mm][kb], b[kb], acc[(mo) + mm][nb], 0, 0, 0); \
  __builtin_amdgcn_s_setprio(0); \
} while (0)

enum { EP_PROJ = 0, EP_EXPERT = 1, EP_CTX = 2, EP_RELU = 3, EP_OUT = 4 };

// Grid: (N/256, M/256). K%64==0, K/64 even and >=2. A rows %256==0, Bt rows %256==0.
template<int EP>
__global__ __launch_bounds__(512, 2)
void gemm8(const u16* __restrict__ A, const u16* __restrict__ Bt,
           const float* __restrict__ bias, void* __restrict__ Cp,
           const float* __restrict__ gate, float* __restrict__ partials,
           int K, int lda, int ldb, int ldc, int nvalid)
{
  extern __shared__ char smem[];   // 131072 B: [dbuf][A 32K | B 32K]
  const int t = threadIdx.x;
  const int lane = t & 63, wid = t >> 6;
  const int wr = wid >> 2, wc = wid & 3;
  const int l31 = lane & 31, lh = lane >> 5;

  // bijective XCD swizzle (nblk % 8 == 0 for all our grids)
  const int nblk = gridDim.x * gridDim.y;
  const int flat = blockIdx.y * gridDim.x + blockIdx.x;
  const int swz = (flat & 7) * (nblk >> 3) + (flat >> 3);
  const int bx = swz % gridDim.x, by = swz / gridDim.x;

  const long a0 = (long)(by * 256) * lda;
  const long b0g = (long)(bx * 256) * ldb;

  facc16 acc[4][2];
#pragma unroll
  for (int m = 0; m < 4; m++)
#pragma unroll
    for (int n = 0; n < 2; n++)
#pragma unroll
      for (int i = 0; i < 16; i++) acc[m][n][i] = 0.f;

  const int r0 = t >> 3, c0s = t & 7;
  const int csw = ((c0s ^ (r0 & 7)) << 3);   // swizzled k-chunk (elems)

  // which: 0=A-half0, 1=A-half1, 2=B-half0, 3=B-half1
  auto STAGE = [&](int kt, int which, int dbuf) {
    const int half = which & 1;
    const u16* gsrc;
    int ld;
    char* ldst = smem + dbuf * 65536 + half * 16384;
    if (which < 2) { gsrc = A + a0; ld = lda; }
    else           { gsrc = Bt + b0g; ld = ldb; ldst += 32768; }
    gsrc += (long)(half * 128 + r0) * ld + kt * 64 + csw;
    gload16(gsrc, ldst + (t << 4));
    gload16(gsrc + 64L * ld, ldst + ((512 + t) << 4));
  };

  const int NT = K >> 6;
  STAGE(0, 0, 0); STAGE(0, 1, 0); STAGE(0, 2, 0); STAGE(0, 3, 0);
  STAGE(1, 0, 1); STAGE(1, 1, 1);
  VMW4(); BARX();

  bfrag8 aE[2][4], aO[2][4], bn0[4], bn1[4];

  for (int it = 0; it < (NT >> 1); ++it) {
    const int T = 2 * it;
    const int tp1 = T + 1;
    const int tp2 = (T + 2 < NT) ? T + 2 : NT - 1;
    const int tp3 = (T + 3 < NT) ? T + 3 : NT - 1;
    // P1: read aE,b0 (buf0=T); stage (T+1).B0 -> buf1; MFMA aE*b0
    RDA32(aE, 0, 0); RDB32(bn0, 0, 0); STAGE(tp1, 2, 1);
    MF32(aE, bn0, 0, 0); BARX();
    // P2: read aO; stage (T+1).B1; MFMA aO*b0
    RDA32(aO, 2, 0); STAGE(tp1, 3, 1);
    MF32(aO, bn0, 2, 0); BARX();
    // P3: read b1; stage (T+2).A0 -> buf0; MFMA aO*b1
    RDB32(bn1, 1, 0); STAGE(tp2, 0, 0);
    MF32(aO, bn1, 2, 1); BARX();
    // P4: stage (T+2).A1 -> buf0; MFMA aE*b1; drain so buf1(T+1) complete
    STAGE(tp2, 1, 0);
    MF32(aE, bn1, 0, 1); VMW4(); BARX();
    // P5-P8: mirror on buf1 (T+1), staging (T+2).B / (T+3).A
    RDA32(aE, 0, 1); RDB32(bn0, 0, 1); STAGE(tp2, 2, 0);
    MF32(aE, bn0, 0, 0); BARX();
    RDA32(aO, 2, 1); STAGE(tp2, 3, 0);
    MF32(aO, bn0, 2, 0); BARX();
    RDB32(bn1, 1, 1); STAGE(tp3, 0, 1);
    MF32(aO, bn1, 2, 1); BARX();
    STAGE(tp3, 1, 1);
    MF32(aE, bn1, 0, 1); VMW4(); BARX();
  }

  // ---- epilogue: drain prefetches (they alias slab space), then LDS restage.
  asm volatile("s_waitcnt vmcnt(0)" ::: "memory");
  __builtin_amdgcn_sched_barrier(0);
  __builtin_amdgcn_s_barrier();
  __builtin_amdgcn_sched_barrier(0);

  const int rbase = by * 256 + wr * 128;
  const int cbase = bx * 256 + wc * 64;
  float* slab = (float*)(smem + wid * 8704);   // per-wave [32][68] f32

  const float bcol0 = bias[cbase + l31];
  const float bcol1 = bias[cbase + 32 + l31];
  const int e0 = cbase >> 7, e1 = (cbase + 32) >> 7;   // expert idx per n-block

#pragma unroll
  for (int pass = 0; pass < 4; ++pass) {   // pass == m-block (32 rows)
    float pr[16];
    if (EP == EP_PROJ) {
#pragma unroll
      for (int reg = 0; reg < 16; ++reg) pr[reg] = 0.f;
    }
#pragma unroll
    for (int nb = 0; nb < 2; ++nb) {
      const float bb = nb ? bcol1 : bcol0;
      const int eidx = nb ? e1 : e0;
      const int gcol = cbase + nb * 32 + l31;
#pragma unroll
      for (int reg = 0; reg < 16; ++reg) {
        const int rowp = (reg & 3) + 8 * (reg >> 2) + 4 * lh;
        const int grow = rbase + pass * 32 + rowp;
        float val = acc[pass][nb][reg] + bb;
        if (EP == EP_EXPERT)
          val = fmaxf(val, 0.f) * gate[(long)grow * 16 + eidx];
        if (EP == EP_CTX && gcol < 20) val *= 2.0f;   // spiking attention
        if (EP == EP_RELU) val = fmaxf(val, 0.f);
        if (EP == EP_PROJ) pr[reg] += val;
        slab[rowp * 68 + nb * 32 + l31] = val;
      }
    }
    if (EP == EP_PROJ) {
#pragma unroll
      for (int reg = 0; reg < 16; ++reg) {
        float p = pr[reg];
        p += __shfl_xor(p, 1); p += __shfl_xor(p, 2);
        p += __shfl_xor(p, 4); p += __shfl_xor(p, 8); p += __shfl_xor(p, 16);
        if (l31 == 0) {
          const int rowp = (reg & 3) + 8 * (reg >> 2) + 4 * lh;
          partials[(long)(rbase + pass * 32 + rowp) * 32 + bx * 4 + wc] = p;
        }
      }
    }
    // wave-private slab; DS ops in-order within a wave (compiler inserts waits)
#pragma unroll
    for (int rep = 0; rep < 4; ++rep) {
      const int rowp = rep * 8 + (lane >> 3);
      const int cc = (lane & 7) * 8;
      const facc4 v0 = *(const facc4*)&slab[rowp * 68 + cc];
      const facc4 v1 = *(const facc4*)&slab[rowp * 68 + cc + 4];
      const long grow = rbase + pass * 32 + rowp;
      const int gcol0 = cbase + cc;
      if (EP == EP_OUT) {
        float* Cf = (float*)Cp;
        if (gcol0 + 7 < nvalid) {
          *(facc4*)(Cf + grow * ldc + gcol0) = v0;
          *(facc4*)(Cf + grow * ldc + gcol0 + 4) = v1;
        } else {
#pragma unroll
          for (int j = 0; j < 4; ++j)
            if (gcol0 + j < nvalid) Cf[grow * ldc + gcol0 + j] = v0[j];
#pragma unroll
          for (int j = 0; j < 4; ++j)
            if (gcol0 + 4 + j < nvalid) Cf[grow * ldc + gcol0 + 4 + j] = v1[j];
        }
      } else {
        u16 o[8];
        o[0] = f2bf(v0[0]); o[1] = f2bf(v0[1]);
        o[2] = f2bf(v0[2]); o[3] = f2bf(v0[3]);
        o[4] = f2bf(v1[0]); o[5] = f2bf(v1[1]);
        o[6] = f2bf(v1[2]); o[7] = f2bf(v1[3]);
        *(uint4*)((u16*)Cp + grow * ldc + gcol0) = *(const uint4*)o;
      }
    }
  }
}

// out[n][k] = bf16(in[k][n]); pads rows n>=N with zeros. Grid: (ceil(N/64), K/64, Z).
__global__ __launch_bounds__(256)
void transpose_conv_k(const float* __restrict__ in, u16* __restrict__ out,
                      int K, int N, int ldout, long in_zstride, int out_zrows)
{
  __shared__ float tile[64][65];
  const int t = threadIdx.x;
  const int n0 = blockIdx.x * 64, k0 = blockIdx.y * 64;
  const float* src = in + (long)blockIdx.z * in_zstride;
  const int rr = t >> 4;
  const int cc = (t & 15) * 4;
#pragma unroll
  for (int j = 0; j < 4; j++) {
    int k = k0 + j * 16 + rr;
    int n = n0 + cc;
    float v0 = 0.f, v1 = 0.f, v2 = 0.f, v3 = 0.f;
    if (n + 3 < N) {
      facc4 v = *(const facc4*)(src + (long)k * N + n);
      v0 = v[0]; v1 = v[1]; v2 = v[2]; v3 = v[3];
    } else {
      if (n < N)     v0 = src[(long)k * N + n];
      if (n + 1 < N) v1 = src[(long)k * N + n + 1];
      if (n + 2 < N) v2 = src[(long)k * N + n + 2];
      if (n + 3 < N) v3 = src[(long)k * N + n + 3];
    }
    float* trow = &tile[j * 16 + rr][cc];
    trow[0] = v0; trow[1] = v1; trow[2] = v2; trow[3] = v3;
  }
  __syncthreads();
  const int n_l = t >> 2;
  const int kc = (t & 3) * 16;
  const int n_gl = n0 + n_l;
  u16 o16[16];
  const bool valid = n_gl < N;
#pragma unroll
  for (int i = 0; i < 16; i++) o16[i] = valid ? f2bf(tile[kc + i][n_l]) : (u16)0;
  long orow = (long)blockIdx.z * out_zrows + n_gl;
  u16* dst = out + orow * (long)ldout + k0 + kc;
  *(uint4*)dst = ((const uint4*)o16)[0];
  *(uint4*)(dst + 8) = ((const uint4*)o16)[1];
}

__global__ __launch_bounds__(256)
void f32_to_bf16_k(const float* __restrict__ in, u16* __restrict__ out)
{
  const long i = ((long)blockIdx.x * 256 + threadIdx.x) * 8;
  facc4 v0 = *(const facc4*)(in + i);
  facc4 v1 = *(const facc4*)(in + i + 4);
  u16 o[8];
  o[0] = f2bf(v0[0]); o[1] = f2bf(v0[1]); o[2] = f2bf(v0[2]); o[3] = f2bf(v0[3]);
  o[4] = f2bf(v1[0]); o[5] = f2bf(v1[1]); o[6] = f2bf(v1[2]); o[7] = f2bf(v1[3]);
  *(uint4*)(out + i) = *(const uint4*)o;
}

__global__ __launch_bounds__(128)
void temporal_k(const float* __restrict__ partials, u16* __restrict__ enh)
{
  __shared__ float tsh;
  const int b = blockIdx.x;
  const int j = threadIdx.x;  // 128
  if (j < 32) {
    float p = partials[(long)b * 32 + j];
    p += __shfl_xor(p, 1); p += __shfl_xor(p, 2); p += __shfl_xor(p, 4);
    p += __shfl_xor(p, 8); p += __shfl_xor(p, 16);
    if (j == 0) tsh = p;
  }
  __syncthreads();
  float tmean = tsh * (1.0f / 2048.0f);
  float v;
  if (j < 64) v = sinf(7.0f * tmean * (float)(j + 1));
  else        v = cosf(7.0f * tmean * (float)(j - 63));
  enh[(long)b * 2176 + 2048 + j] = f2bf(v);
}

// gate = softmax(enh @ Wg + bg); 8 rows/block staged in LDS once.
__global__ __launch_bounds__(128)
void gate_k(const u16* __restrict__ enh, const float* __restrict__ Wg,
            const float* __restrict__ bg, float* __restrict__ gate)
{
  __shared__ u16 lds[8][2184];   // +8 pad: banks spread
  const int t = threadIdx.x;
  const long row0 = (long)blockIdx.x * 8;
#pragma unroll
  for (int r8 = 0; r8 < 8; ++r8) {
    const u16* src = enh + (row0 + r8) * 2176;
    u16* dst = &lds[r8][0];
    *(uint4*)(dst + t * 8) = *(const uint4*)(src + t * 8);
    *(uint4*)(dst + (128 + t) * 8) = *(const uint4*)(src + (128 + t) * 8);
    if (t < 16)
      *(uint4*)(dst + (256 + t) * 8) = *(const uint4*)(src + (256 + t) * 8);
  }
  __syncthreads();
  const int r = t >> 4, e = t & 15;
  float acc = bg[e];
  for (int k = 0; k < 2176; k += 8) {
    uint4 a = *(const uint4*)&lds[r][k];
    const u16* ap = (const u16*)&a;
#pragma unroll
    for (int j = 0; j < 8; ++j)
      acc += bf2f(ap[j]) * Wg[(k + j) * 16 + e];
  }
  float mx = acc;
  mx = fmaxf(mx, __shfl_xor(mx, 8)); mx = fmaxf(mx, __shfl_xor(mx, 4));
  mx = fmaxf(mx, __shfl_xor(mx, 2)); mx = fmaxf(mx, __shfl_xor(mx, 1));
  float ex = expf(acc - mx);
  float sum = ex;
  sum += __shfl_xor(sum, 8); sum += __shfl_xor(sum, 4);
  sum += __shfl_xor(sum, 2); sum += __shfl_xor(sum, 1);
  gate[(row0 + r) * 16 + e] = ex / sum;
}

// comb[b][k] = sum_e expw[b][e*128+k], 8 k's per thread
__global__ __launch_bounds__(256)
void combine_k(const u16* __restrict__ expw, u16* __restrict__ comb)
{
  const long i = ((long)blockIdx.x * 256 + threadIdx.x) * 8;
  const long b = i >> 7;
  const int k = (int)(i & 127);
  float s[8] = {0.f, 0.f, 0.f, 0.f, 0.f, 0.f, 0.f, 0.f};
#pragma unroll
  for (int e = 0; e < 16; ++e) {
    uint4 v = *(const uint4*)(expw + b * 2048 + e * 128 + k);
    const u16* vp = (const u16*)&v;
#pragma unroll
    for (int j = 0; j < 8; ++j) s[j] += bf2f(vp[j]);
  }
  u16 o[8];
#pragma unroll
  for (int j = 0; j < 8; ++j) o[j] = f2bf(s[j]);
  *(uint4*)(comb + i) = *(const uint4*)o;
}

extern "C" void kernel_launch(void* const* d_in, const int* in_sizes, int n_in,
                              void* d_out, int out_size, void* d_ws,
                              size_t ws_size, hipStream_t stream)
{
  const float* x    = (const float*)d_in[0];
  const float* W_in = (const float*)d_in[1];
  const float* b_in = (const float*)d_in[2];
  const float* Wg   = (const float*)d_in[3];
  const float* bg   = (const float*)d_in[4];
  const float* We   = (const float*)d_in[5];
  const float* be   = (const float*)d_in[6];
  const float* Wo   = (const float*)d_in[7];
  const float* bo   = (const float*)d_in[8];
  const float* Wh   = (const float*)d_in[9];
  const float* bh   = (const float*)d_in[10];
  const float* Wcls = (const float*)d_in[11];
  const float* bcls = (const float*)d_in[12];
  float* out = (float*)d_out;

  char* ws = (char*)d_ws;
  u16* enhb   = (u16*)(ws);                    // 35,651,584  [8192][2176]
  u16* bufF   = (u16*)(ws + 35651584);         // 33,554,432  Wt_in+xb -> expw/h1/h3
  u16* bufA   = (u16*)(ws + 69206016);         //  8,912,896  Wt_e -> Wt_cls
  u16* Wt_o   = (u16*)(ws + 78118912);         //    524,288  [2048][128]
  u16* bufW1  = (u16*)(ws + 78643200);         //  8,388,608  Wh0 -> Wh2
  u16* bufW2  = (u16*)(ws + 87031808);         //  8,388,608  Wh1
  u16* comb   = (u16*)(ws + 95420416);         //  2,097,152  [8192][128]
  float* partials = (float*)(ws + 97517568);   //  1,048,576
  float* gate     = (float*)(ws + 98566144);   //    524,288
  u16* Wt_in  = bufF;                          // [2048][1024], dead after proj
  u16* xb     = bufF + 2097152;                // [8192][1024] bf16, dead after proj
  u16* Wt_e   = bufA;                          // [2048][2176], dead after expert
  u16* Wt_cls = bufA;                          // [1024][2048]

  hipFuncSetAttribute((const void*)gemm8<EP_PROJ>,
                      hipFuncAttributeMaxDynamicSharedMemorySize, 131072);
  hipFuncSetAttribute((const void*)gemm8<EP_EXPERT>,
                      hipFuncAttributeMaxDynamicSharedMemorySize, 131072);
  hipFuncSetAttribute((const void*)gemm8<EP_CTX>,
                      hipFuncAttributeMaxDynamicSharedMemorySize, 131072);
  hipFuncSetAttribute((const void*)gemm8<EP_RELU>,
                      hipFuncAttributeMaxDynamicSharedMemorySize, 131072);
  hipFuncSetAttribute((const void*)gemm8<EP_OUT>,
                      hipFuncAttributeMaxDynamicSharedMemorySize, 131072);

  // ---- conversions needed before the first GEMMs
  f32_to_bf16_k<<<4096, 256, 0, stream>>>(x, xb);
  transpose_conv_k<<<dim3(32, 16, 1), 256, 0, stream>>>(W_in, Wt_in, 1024, 2048, 1024, 0, 0);
  transpose_conv_k<<<dim3(2, 34, 16), 256, 0, stream>>>(We, Wt_e, 2176, 128, 2176, 2176L * 128L, 128);
  transpose_conv_k<<<dim3(32, 2, 1), 256, 0, stream>>>(Wo, Wt_o, 128, 2048, 128, 0, 0);
  // Wh0 -> bufW1, Wh1 -> bufW2 (contiguous): one z=2 launch
  transpose_conv_k<<<dim3(32, 32, 2), 256, 0, stream>>>(Wh, bufW1, 2048, 2048, 2048, 2048L * 2048L, 2048);

  // 1) proj = x @ W_in + b_in -> enhb[:, :2048] + row partial sums
  gemm8<EP_PROJ><<<dim3(8, 32), 512, 131072, stream>>>(
      xb, Wt_in, b_in, (void*)enhb, nullptr, partials, 1024, 1024, 1024, 2176, 2048);
  // 2) phasor bank -> enhb[:, 2048:]
  temporal_k<<<8192, 128, 0, stream>>>(partials, enhb);
  // 3) softmax gate
  gate_k<<<1024, 128, 0, stream>>>(enhb, Wg, bg, gate);
  // 4) experts: relu(enh @ We + be) * gate
  gemm8<EP_EXPERT><<<dim3(8, 32), 512, 131072, stream>>>(
      enhb, Wt_e, be, (void*)bufF, gate, nullptr, 2176, 2176, 2176, 2048, 2048);
  // Wt_e dead -> convert Wcls into bufA
  transpose_conv_k<<<dim3(16, 32, 1), 256, 0, stream>>>(Wcls, Wt_cls, 2048, 1000, 2048, 0, 0);
  // 5) combine experts
  combine_k<<<512, 256, 0, stream>>>(bufF, comb);
  // 6) context = comb @ Wo + bo, cols<20 doubled -> attended (enhb region)
  gemm8<EP_CTX><<<dim3(8, 32), 512, 131072, stream>>>(
      comb, Wt_o, bo, (void*)enhb, nullptr, nullptr, 128, 128, 128, 2048, 2048);
  // 7) MLP: h1 -> bufF, h2 -> enhb, h3 -> bufF
  gemm8<EP_RELU><<<dim3(8, 32), 512, 131072, stream>>>(
      enhb, bufW1, bh, (void*)bufF, nullptr, nullptr, 2048, 2048, 2048, 2048, 2048);
  transpose_conv_k<<<dim3(32, 32, 1), 256, 0, stream>>>(Wh + 2L * 2048L * 2048L, bufW1, 2048, 2048, 2048, 0, 0);
  gemm8<EP_RELU><<<dim3(8, 32), 512, 131072, stream>>>(
      bufF, bufW2, bh + 2048, (void*)enhb, nullptr, nullptr, 2048, 2048, 2048, 2048, 2048);
  gemm8<EP_RELU><<<dim3(8, 32), 512, 131072, stream>>>(
      enhb, bufW1, bh + 4096, (void*)bufF, nullptr, nullptr, 2048, 2048, 2048, 2048, 2048);
  // 8) logits (N=1000 -> padded 1024; Wt_cls rows >=1000 are zero; stores masked)
  gemm8<EP_OUT><<<dim3(4, 32), 512, 131072, stream>>>(
      bufF, Wt_cls, bcls, (void*)out, nullptr, nullptr, 2048, 2048, 2048, 1000, 1000);
}

// Round 8
// 432.969 us; speedup vs baseline: 1.1143x; 1.1143x over previous
//
#include <hip/hip_runtime.h>
#include <math.h>

// ---------------------------------------------------------------------------
// SophisticatedBioInspiredModel — bf16 MFMA (16x16x32), 256^2 8-phase GEMMs
// with cross-phase fragment prefetch (gfx950).
//
// Spiking attention is data-independent: 100 distinct tokens, each bumped once
// from decayed-zero -> v=1.0 < 1.2 -> no spikes -> counts==0 -> top_k(zeros,20)
// = indices 0..19 -> gains double cols 0..19 of context.
//
// GEMM: C = A(MxK,bf16) * Bt(NxK,bf16)^T. 256x256 tile, BK=64, 8 waves (2Mx4N),
// 128 KiB LDS double-buffer, 8 phases / 2 K-tiles, counted vmcnt(4) at P4/P8
// only, chunk^(row&7) swizzle (conflict-free for the 16x16 fragment pattern —
// 32x32 frags are inherently 4-way-conflicted, measured r7), setprio, XCD
// swizzle. NEW: phase p issues ds_reads for phase p+1's fragments, so MFMA
// clusters run with operands resident and LDS reads hide under MFMA.
// ---------------------------------------------------------------------------

typedef unsigned short u16;
typedef __attribute__((ext_vector_type(8))) short bfrag8;
typedef __attribute__((ext_vector_type(4))) float facc4;

__device__ __forceinline__ u16 f2bf(float f) {
  union { float f; unsigned u; } c; c.f = f;
  unsigned u = c.u;
  return (u16)((u + 0x7fffu + ((u >> 16) & 1u)) >> 16);
}
__device__ __forceinline__ float bf2f(u16 h) {
  union { unsigned u; float f; } c; c.u = ((unsigned)h) << 16;
  return c.f;
}
__device__ __forceinline__ void gload16(const void* g, void* lds) {
  __builtin_amdgcn_global_load_lds(
      (const __attribute__((address_space(1))) unsigned*)g,
      (__attribute__((address_space(3))) unsigned*)lds, 16, 0, 0);
}

#define BARX() do { __builtin_amdgcn_sched_barrier(0); \
  __builtin_amdgcn_s_barrier(); __builtin_amdgcn_sched_barrier(0); } while (0)
#define VMW4() do { asm volatile("s_waitcnt vmcnt(4)" ::: "memory"); \
  __builtin_amdgcn_sched_barrier(0); } while (0)

#define RDA_(dst, mbase, dbuf) do { \
  char* _b = smem + (dbuf) * 65536; \
  _Pragma("unroll") for (int mm = 0; mm < 4; ++mm) { \
    int _row = wr * 128 + ((mbase) + mm) * 16 + r15; \
    _Pragma("unroll") for (int ks = 0; ks < 2; ++ks) \
      dst[mm][ks] = *(const bfrag8*)(_b + _row * 128 + \
                                     (((g + ks * 4) ^ (_row & 7)) << 4)); \
  } } while (0)

#define RDB_(dst, nbase, dbuf) do { \
  char* _b = smem + (dbuf) * 65536 + 32768; \
  _Pragma("unroll") for (int nn = 0; nn < 2; ++nn) { \
    int _row = wc * 64 + ((nbase) + nn) * 16 + r15; \
    _Pragma("unroll") for (int ks = 0; ks < 2; ++ks) \
      dst[nn][ks] = *(const bfrag8*)(_b + _row * 128 + \
                                     (((g + ks * 4) ^ (_row & 7)) << 4)); \
  } } while (0)

#define MF_(a, b, mo, no) do { \
  __builtin_amdgcn_s_setprio(1); \
  _Pragma("unroll") for (int mm = 0; mm < 4; ++mm) \
  _Pragma("unroll") for (int nn = 0; nn < 2; ++nn) \
  _Pragma("unroll") for (int ks = 0; ks < 2; ++ks) \
    acc[(mo) + mm][(no) + nn] = __builtin_amdgcn_mfma_f32_16x16x32_bf16( \
        a[mm][ks], b[nn][ks], acc[(mo) + mm][(no) + nn], 0, 0, 0); \
  __builtin_amdgcn_s_setprio(0); \
} while (0)

enum { EP_PROJ = 0, EP_EXPERT = 1, EP_CTX = 2, EP_RELU = 3, EP_OUT = 4 };

// Grid: (N/256, M/256). K%64==0, K/64 even and >=2. A rows %256==0, Bt rows %256==0.
template<int EP>
__global__ __launch_bounds__(512, 2)
void gemm8(const u16* __restrict__ A, const u16* __restrict__ Bt,
           const float* __restrict__ bias, void* __restrict__ Cp,
           const float* __restrict__ gate, float* __restrict__ partials,
           int K, int lda, int ldb, int ldc, int nvalid)
{
  extern __shared__ char smem[];   // 131072 B: [dbuf][A 32K | B 32K]
  const int t = threadIdx.x;
  const int lane = t & 63, wid = t >> 6;
  const int wr = wid >> 2, wc = wid & 3;
  const int g = lane >> 4, r15 = lane & 15;

  // bijective XCD swizzle (nblk % 8 == 0 for all our grids)
  const int nblk = gridDim.x * gridDim.y;
  const int flat = blockIdx.y * gridDim.x + blockIdx.x;
  const int swz = (flat & 7) * (nblk >> 3) + (flat >> 3);
  const int bx = swz % gridDim.x, by = swz / gridDim.x;

  const long a0 = (long)(by * 256) * lda;
  const long b0 = (long)(bx * 256) * ldb;

  facc4 acc[8][4];
#pragma unroll
  for (int m = 0; m < 8; m++)
#pragma unroll
    for (int n = 0; n < 4; n++) acc[m][n] = (facc4){0.f, 0.f, 0.f, 0.f};

  const int r0 = t >> 3, c0s = t & 7;
  const int csw = ((c0s ^ (r0 & 7)) << 3);   // swizzled k-chunk (elems)

  // which: 0=A-half0, 1=A-half1, 2=B-half0, 3=B-half1
  auto STAGE = [&](int kt, int which, int dbuf) {
    const int half = which & 1;
    const u16* gsrc;
    int ld;
    char* ldst = smem + dbuf * 65536 + half * 16384;
    if (which < 2) { gsrc = A + a0; ld = lda; }
    else           { gsrc = Bt + b0; ld = ldb; ldst += 32768; }
    gsrc += (long)(half * 128 + r0) * ld + kt * 64 + csw;
    gload16(gsrc, ldst + (t << 4));
    gload16(gsrc + 64L * ld, ldst + ((512 + t) << 4));
  };

  const int NT = K >> 6;
  STAGE(0, 0, 0); STAGE(0, 1, 0); STAGE(0, 2, 0); STAGE(0, 3, 0);
  STAGE(1, 0, 1); STAGE(1, 1, 1);
  VMW4(); BARX();

  bfrag8 aE[4][2], aO[4][2], b01[2][2], b23[2][2];

  // pre-loop prefetch for P1 (buf0 = tile 0, fully landed)
  RDA_(aE, 0, 0); RDB_(b01, 0, 0);

  for (int it = 0; it < (NT >> 1); ++it) {
    const int T = 2 * it;
    const int tp1 = T + 1;
    const int tp2 = (T + 2 < NT) ? T + 2 : NT - 1;
    const int tp3 = (T + 3 < NT) ? T + 3 : NT - 1;
    // P1: MFMA aE*b01 (prefetched); stage (T+1).B0 -> buf1; prefetch aO(buf0)
    STAGE(tp1, 2, 1);
    MF_(aE, b01, 0, 0); RDA_(aO, 4, 0); BARX();
    // P2: MFMA aO*b01; stage (T+1).B1; prefetch b23(buf0)
    STAGE(tp1, 3, 1);
    MF_(aO, b01, 4, 0); RDB_(b23, 2, 0); BARX();
    // P3: MFMA aO*b23; stage (T+2).A0 -> buf0 (all buf0.A reads done @P2-end)
    STAGE(tp2, 0, 0);
    MF_(aO, b23, 4, 2); BARX();
    // P4: MFMA aE*b23; stage (T+2).A1; drain so buf1(T+1) complete
    STAGE(tp2, 1, 0);
    MF_(aE, b23, 0, 2); VMW4(); BARX();
    // P5: serial read aE,b01 from buf1(T+1); stage (T+2).B0 -> buf0; MFMA;
    //     prefetch aO(buf1)
    RDA_(aE, 0, 1); RDB_(b01, 0, 1); STAGE(tp2, 2, 0);
    MF_(aE, b01, 0, 0); RDA_(aO, 4, 1); BARX();
    // P6
    STAGE(tp2, 3, 0);
    MF_(aO, b01, 4, 0); RDB_(b23, 2, 1); BARX();
    // P7
    STAGE(tp3, 0, 1);
    MF_(aO, b23, 4, 2); BARX();
    // P8: drain so buf0(T+2) complete, then prefetch next-P1 frags from buf0
    STAGE(tp3, 1, 1);
    MF_(aE, b23, 0, 2); VMW4(); BARX();
    RDA_(aE, 0, 0); RDB_(b01, 0, 0);
  }

  // ---- epilogue: drain prefetches (they alias slab space), then LDS restage.
  asm volatile("s_waitcnt vmcnt(0)" ::: "memory");
  __builtin_amdgcn_sched_barrier(0);
  __builtin_amdgcn_s_barrier();
  __builtin_amdgcn_sched_barrier(0);

  const int rbase = by * 256 + wr * 128;
  const int cbase = bx * 256 + wc * 64;
  float* slab = (float*)(smem + wid * 8704);   // per-wave [32][68] f32

  float psum[8][4];
  if (EP == EP_PROJ) {
#pragma unroll
    for (int m = 0; m < 8; m++)
#pragma unroll
      for (int r = 0; r < 4; r++) psum[m][r] = 0.f;
  }

#pragma unroll
  for (int pass = 0; pass < 4; ++pass) {
#pragma unroll
    for (int mm = 0; mm < 2; ++mm) {
      const int m = pass * 2 + mm;
#pragma unroll
      for (int n = 0; n < 4; ++n)
#pragma unroll
        for (int r = 0; r < 4; ++r) {
          const int rowp = mm * 16 + g * 4 + r;
          const int grow = rbase + m * 16 + g * 4 + r;
          const int gcol = cbase + n * 16 + r15;
          float val = acc[m][n][r] + bias[gcol];
          if (EP == EP_EXPERT)
            val = fmaxf(val, 0.f) * gate[(long)grow * 16 + (gcol >> 7)];
          if (EP == EP_CTX && gcol < 20) val *= 2.0f;   // spiking attention
          if (EP == EP_RELU) val = fmaxf(val, 0.f);
          if (EP == EP_PROJ) psum[m][r] += val;
          slab[rowp * 68 + n * 16 + r15] = val;
        }
    }
    // wave-private slab; DS ops in-order within a wave (compiler inserts waits)
#pragma unroll
    for (int rep = 0; rep < 4; ++rep) {
      const int rowp = rep * 8 + (lane >> 3);
      const int cc = (lane & 7) * 8;
      const facc4 v0 = *(const facc4*)&slab[rowp * 68 + cc];
      const facc4 v1 = *(const facc4*)&slab[rowp * 68 + cc + 4];
      const long grow = rbase + pass * 32 + rowp;
      const int gcol0 = cbase + cc;
      if (EP == EP_OUT) {
        float* Cf = (float*)Cp;
        if (gcol0 + 7 < nvalid) {
          *(facc4*)(Cf + grow * ldc + gcol0) = v0;
          *(facc4*)(Cf + grow * ldc + gcol0 + 4) = v1;
        } else {
#pragma unroll
          for (int j = 0; j < 4; ++j)
            if (gcol0 + j < nvalid) Cf[grow * ldc + gcol0 + j] = v0[j];
#pragma unroll
          for (int j = 0; j < 4; ++j)
            if (gcol0 + 4 + j < nvalid) Cf[grow * ldc + gcol0 + 4 + j] = v1[j];
        }
      } else {
        u16 o[8];
        o[0] = f2bf(v0[0]); o[1] = f2bf(v0[1]);
        o[2] = f2bf(v0[2]); o[3] = f2bf(v0[3]);
        o[4] = f2bf(v1[0]); o[5] = f2bf(v1[1]);
        o[6] = f2bf(v1[2]); o[7] = f2bf(v1[3]);
        *(uint4*)((u16*)Cp + grow * ldc + gcol0) = *(const uint4*)o;
      }
    }
  }

  if (EP == EP_PROJ) {
#pragma unroll
    for (int m = 0; m < 8; m++)
#pragma unroll
      for (int r = 0; r < 4; r++) {
        float p = psum[m][r];
        p += __shfl_xor(p, 1); p += __shfl_xor(p, 2);
        p += __shfl_xor(p, 4); p += __shfl_xor(p, 8);
        if (r15 == 0)
          partials[(long)(rbase + m * 16 + g * 4 + r) * 32 + bx * 4 + wc] = p;
      }
  }
}

// out[n][k] = bf16(in[k][n]); pads rows n>=N with zeros. Grid: (ceil(N/64), K/64, Z).
__global__ __launch_bounds__(256)
void transpose_conv_k(const float* __restrict__ in, u16* __restrict__ out,
                      int K, int N, int ldout, long in_zstride, int out_zrows)
{
  __shared__ float tile[64][65];
  const int t = threadIdx.x;
  const int n0 = blockIdx.x * 64, k0 = blockIdx.y * 64;
  const float* src = in + (long)blockIdx.z * in_zstride;
  const int rr = t >> 4;
  const int cc = (t & 15) * 4;
#pragma unroll
  for (int j = 0; j < 4; j++) {
    int k = k0 + j * 16 + rr;
    int n = n0 + cc;
    float v0 = 0.f, v1 = 0.f, v2 = 0.f, v3 = 0.f;
    if (n + 3 < N) {
      facc4 v = *(const facc4*)(src + (long)k * N + n);
      v0 = v[0]; v1 = v[1]; v2 = v[2]; v3 = v[3];
    } else {
      if (n < N)     v0 = src[(long)k * N + n];
      if (n + 1 < N) v1 = src[(long)k * N + n + 1];
      if (n + 2 < N) v2 = src[(long)k * N + n + 2];
      if (n + 3 < N) v3 = src[(long)k * N + n + 3];
    }
    float* trow = &tile[j * 16 + rr][cc];
    trow[0] = v0; trow[1] = v1; trow[2] = v2; trow[3] = v3;
  }
  __syncthreads();
  const int n_l = t >> 2;
  const int kc = (t & 3) * 16;
  const int n_gl = n0 + n_l;
  u16 o16[16];
  const bool valid = n_gl < N;
#pragma unroll
  for (int i = 0; i < 16; i++) o16[i] = valid ? f2bf(tile[kc + i][n_l]) : (u16)0;
  long orow = (long)blockIdx.z * out_zrows + n_gl;
  u16* dst = out + orow * (long)ldout + k0 + kc;
  *(uint4*)dst = ((const uint4*)o16)[0];
  *(uint4*)(dst + 8) = ((const uint4*)o16)[1];
}

__global__ __launch_bounds__(256)
void f32_to_bf16_k(const float* __restrict__ in, u16* __restrict__ out)
{
  const long i = ((long)blockIdx.x * 256 + threadIdx.x) * 8;
  facc4 v0 = *(const facc4*)(in + i);
  facc4 v1 = *(const facc4*)(in + i + 4);
  u16 o[8];
  o[0] = f2bf(v0[0]); o[1] = f2bf(v0[1]); o[2] = f2bf(v0[2]); o[3] = f2bf(v0[3]);
  o[4] = f2bf(v1[0]); o[5] = f2bf(v1[1]); o[6] = f2bf(v1[2]); o[7] = f2bf(v1[3]);
  *(uint4*)(out + i) = *(const uint4*)o;
}

__global__ __launch_bounds__(128)
void temporal_k(const float* __restrict__ partials, u16* __restrict__ enh)
{
  __shared__ float tsh;
  const int b = blockIdx.x;
  const int j = threadIdx.x;  // 128
  if (j < 32) {
    float p = partials[(long)b * 32 + j];
    p += __shfl_xor(p, 1); p += __shfl_xor(p, 2); p += __shfl_xor(p, 4);
    p += __shfl_xor(p, 8); p += __shfl_xor(p, 16);
    if (j == 0) tsh = p;
  }
  __syncthreads();
  float tmean = tsh * (1.0f / 2048.0f);
  float v;
  if (j < 64) v = sinf(7.0f * tmean * (float)(j + 1));
  else        v = cosf(7.0f * tmean * (float)(j - 63));
  enh[(long)b * 2176 + 2048 + j] = f2bf(v);
}

// gate = softmax(enh @ Wg + bg); 8 rows/block staged in LDS once.
__global__ __launch_bounds__(128)
void gate_k(const u16* __restrict__ enh, const float* __restrict__ Wg,
            const float* __restrict__ bg, float* __restrict__ gate)
{
  __shared__ u16 lds[8][2184];   // +8 pad: banks spread
  const int t = threadIdx.x;
  const long row0 = (long)blockIdx.x * 8;
#pragma unroll
  for (int r8 = 0; r8 < 8; ++r8) {
    const u16* src = enh + (row0 + r8) * 2176;
    u16* dst = &lds[r8][0];
    *(uint4*)(dst + t * 8) = *(const uint4*)(src + t * 8);
    *(uint4*)(dst + (128 + t) * 8) = *(const uint4*)(src + (128 + t) * 8);
    if (t < 16)
      *(uint4*)(dst + (256 + t) * 8) = *(const uint4*)(src + (256 + t) * 8);
  }
  __syncthreads();
  const int r = t >> 4, e = t & 15;
  float acc = bg[e];
  for (int k = 0; k < 2176; k += 8) {
    uint4 a = *(const uint4*)&lds[r][k];
    const u16* ap = (const u16*)&a;
#pragma unroll
    for (int j = 0; j < 8; ++j)
      acc += bf2f(ap[j]) * Wg[(k + j) * 16 + e];
  }
  float mx = acc;
  mx = fmaxf(mx, __shfl_xor(mx, 8)); mx = fmaxf(mx, __shfl_xor(mx, 4));
  mx = fmaxf(mx, __shfl_xor(mx, 2)); mx = fmaxf(mx, __shfl_xor(mx, 1));
  float ex = expf(acc - mx);
  float sum = ex;
  sum += __shfl_xor(sum, 8); sum += __shfl_xor(sum, 4);
  sum += __shfl_xor(sum, 2); sum += __shfl_xor(sum, 1);
  gate[(row0 + r) * 16 + e] = ex / sum;
}

// comb[b][k] = sum_e expw[b][e*128+k], 8 k's per thread
__global__ __launch_bounds__(256)
void combine_k(const u16* __restrict__ expw, u16* __restrict__ comb)
{
  const long i = ((long)blockIdx.x * 256 + threadIdx.x) * 8;
  const long b = i >> 7;
  const int k = (int)(i & 127);
  float s[8] = {0.f, 0.f, 0.f, 0.f, 0.f, 0.f, 0.f, 0.f};
#pragma unroll
  for (int e = 0; e < 16; ++e) {
    uint4 v = *(const uint4*)(expw + b * 2048 + e * 128 + k);
    const u16* vp = (const u16*)&v;
#pragma unroll
    for (int j = 0; j < 8; ++j) s[j] += bf2f(vp[j]);
  }
  u16 o[8];
#pragma unroll
  for (int j = 0; j < 8; ++j) o[j] = f2bf(s[j]);
  *(uint4*)(comb + i) = *(const uint4*)o;
}

extern "C" void kernel_launch(void* const* d_in, const int* in_sizes, int n_in,
                              void* d_out, int out_size, void* d_ws,
                              size_t ws_size, hipStream_t stream)
{
  const float* x    = (const float*)d_in[0];
  const float* W_in = (const float*)d_in[1];
  const float* b_in = (const float*)d_in[2];
  const float* Wg   = (const float*)d_in[3];
  const float* bg   = (const float*)d_in[4];
  const float* We   = (const float*)d_in[5];
  const float* be   = (const float*)d_in[6];
  const float* Wo   = (const float*)d_in[7];
  const float* bo   = (const float*)d_in[8];
  const float* Wh   = (const float*)d_in[9];
  const float* bh   = (const float*)d_in[10];
  const float* Wcls = (const float*)d_in[11];
  const float* bcls = (const float*)d_in[12];
  float* out = (float*)d_out;

  char* ws = (char*)d_ws;
  u16* enhb   = (u16*)(ws);                    // 35,651,584  [8192][2176]
  u16* bufF   = (u16*)(ws + 35651584);         // 33,554,432  Wt_in+xb -> expw/h1/h3
  u16* bufA   = (u16*)(ws + 69206016);         //  8,912,896  Wt_e -> Wt_cls
  u16* Wt_o   = (u16*)(ws + 78118912);         //    524,288  [2048][128]
  u16* bufW1  = (u16*)(ws + 78643200);         //  8,388,608  Wh0 -> Wh2
  u16* bufW2  = (u16*)(ws + 87031808);         //  8,388,608  Wh1
  u16* comb   = (u16*)(ws + 95420416);         //  2,097,152  [8192][128]
  float* partials = (float*)(ws + 97517568);   //  1,048,576
  float* gate     = (float*)(ws + 98566144);   //    524,288
  u16* Wt_in  = bufF;                          // [2048][1024], dead after proj
  u16* xb     = bufF + 2097152;                // [8192][1024] bf16, dead after proj
  u16* Wt_e   = bufA;                          // [2048][2176], dead after expert
  u16* Wt_cls = bufA;                          // [1024][2048]

  hipFuncSetAttribute((const void*)gemm8<EP_PROJ>,
                      hipFuncAttributeMaxDynamicSharedMemorySize, 131072);
  hipFuncSetAttribute((const void*)gemm8<EP_EXPERT>,
                      hipFuncAttributeMaxDynamicSharedMemorySize, 131072);
  hipFuncSetAttribute((const void*)gemm8<EP_CTX>,
                      hipFuncAttributeMaxDynamicSharedMemorySize, 131072);
  hipFuncSetAttribute((const void*)gemm8<EP_RELU>,
                      hipFuncAttributeMaxDynamicSharedMemorySize, 131072);
  hipFuncSetAttribute((const void*)gemm8<EP_OUT>,
                      hipFuncAttributeMaxDynamicSharedMemorySize, 131072);

  // ---- conversions needed before the first GEMMs
  f32_to_bf16_k<<<4096, 256, 0, stream>>>(x, xb);
  transpose_conv_k<<<dim3(32, 16, 1), 256, 0, stream>>>(W_in, Wt_in, 1024, 2048, 1024, 0, 0);
  transpose_conv_k<<<dim3(2, 34, 16), 256, 0, stream>>>(We, Wt_e, 2176, 128, 2176, 2176L * 128L, 128);
  transpose_conv_k<<<dim3(32, 2, 1), 256, 0, stream>>>(Wo, Wt_o, 128, 2048, 128, 0, 0);
  // Wh0 -> bufW1, Wh1 -> bufW2 (contiguous): one z=2 launch
  transpose_conv_k<<<dim3(32, 32, 2), 256, 0, stream>>>(Wh, bufW1, 2048, 2048, 2048, 2048L * 2048L, 2048);

  // 1) proj = x @ W_in + b_in -> enhb[:, :2048] + row partial sums
  gemm8<EP_PROJ><<<dim3(8, 32), 512, 131072, stream>>>(
      xb, Wt_in, b_in, (void*)enhb, nullptr, partials, 1024, 1024, 1024, 2176, 2048);
  // 2) phasor bank -> enhb[:, 2048:]
  temporal_k<<<8192, 128, 0, stream>>>(partials, enhb);
  // 3) softmax gate
  gate_k<<<1024, 128, 0, stream>>>(enhb, Wg, bg, gate);
  // 4) experts: relu(enh @ We + be) * gate
  gemm8<EP_EXPERT><<<dim3(8, 32), 512, 131072, stream>>>(
      enhb, Wt_e, be, (void*)bufF, gate, nullptr, 2176, 2176, 2176, 2048, 2048);
  // Wt_e dead -> convert Wcls into bufA
  transpose_conv_k<<<dim3(16, 32, 1), 256, 0, stream>>>(Wcls, Wt_cls, 2048, 1000, 2048, 0, 0);
  // 5) combine experts
  combine_k<<<512, 256, 0, stream>>>(bufF, comb);
  // 6) context = comb @ Wo + bo, cols<20 doubled -> attended (enhb region)
  gemm8<EP_CTX><<<dim3(8, 32), 512, 131072, stream>>>(
      comb, Wt_o, bo, (void*)enhb, nullptr, nullptr, 128, 128, 128, 2048, 2048);
  // 7) MLP: h1 -> bufF, h2 -> enhb, h3 -> bufF
  gemm8<EP_RELU><<<dim3(8, 32), 512, 131072, stream>>>(
      enhb, bufW1, bh, (void*)bufF, nullptr, nullptr, 2048, 2048, 2048, 2048, 2048);
  transpose_conv_k<<<dim3(32, 32, 1), 256, 0, stream>>>(Wh + 2L * 2048L * 2048L, bufW1, 2048, 2048, 2048, 0, 0);
  gemm8<EP_RELU><<<dim3(8, 32), 512, 131072, stream>>>(
      bufF, bufW2, bh + 2048, (void*)enhb, nullptr, nullptr, 2048, 2048, 2048, 2048, 2048);
  gemm8<EP_RELU><<<dim3(8, 32), 512, 131072, stream>>>(
      enhb, bufW1, bh + 4096, (void*)bufF, nullptr, nullptr, 2048, 2048, 2048, 2048, 2048);
  // 8) logits (N=1000 -> padded 1024; Wt_cls rows >=1000 are zero; stores masked)
  gemm8<EP_OUT><<<dim3(4, 32), 512, 131072, stream>>>(
      bufF, Wt_cls, bcls, (void*)out, nullptr, nullptr, 2048, 2048, 2048, 1000, 1000);
}

// Round 9
// 411.731 us; speedup vs baseline: 1.1718x; 1.0516x over previous
//
#include <hip/hip_runtime.h>
#include <math.h>

// ---------------------------------------------------------------------------
// SophisticatedBioInspiredModel — bf16 MFMA (16x16x32), 6-phase GEMMs (gfx950).
//
// Spiking attention is data-independent: 100 distinct tokens, each bumped once
// from decayed-zero -> v=1.0 < 1.2 -> no spikes -> counts==0 -> top_k(zeros,20)
// = indices 0..19 -> gains double cols 0..19 of context.
//
// GEMM: C = A(MxK,bf16) * Bt(NxK,bf16)^T. Template MFR = m-frags/wave:
//   MFR=8: 256x256 tile, 128 KiB LDS (measured-best r5 schedule, 66.9 us)
//   MFR=4: 128x256 tile,  96 KiB LDS — for the N=1000 logits GEMM so the
//          grid is 256 blocks (full CU utilization) instead of 128.
// 6-phase / 2 K-tiles, counted vmcnt(MFR/2) at P3/P6 (never 0 in loop),
// chunk^(row&7) swizzle (conflict-free for 16x16 frags; 32x32 is inherently
// 4-way-conflicted — measured r7), setprio, bijective XCD swizzle,
// LDS-restaged coalesced stores.
// ---------------------------------------------------------------------------

typedef unsigned short u16;
typedef __attribute__((ext_vector_type(8))) short bfrag8;
typedef __attribute__((ext_vector_type(4))) float facc4;

__device__ __forceinline__ u16 f2bf(float f) {
  union { float f; unsigned u; } c; c.f = f;
  unsigned u = c.u;
  return (u16)((u + 0x7fffu + ((u >> 16) & 1u)) >> 16);
}
__device__ __forceinline__ float bf2f(u16 h) {
  union { unsigned u; float f; } c; c.u = ((unsigned)h) << 16;
  return c.f;
}
__device__ __forceinline__ void gload16(const void* g, void* lds) {
  __builtin_amdgcn_global_load_lds(
      (const __attribute__((address_space(1))) unsigned*)g,
      (__attribute__((address_space(3))) unsigned*)lds, 16, 0, 0);
}

#define BARX() do { __builtin_amdgcn_sched_barrier(0); \
  __builtin_amdgcn_s_barrier(); __builtin_amdgcn_sched_barrier(0); } while (0)
#define LGKM0() do { asm volatile("s_waitcnt lgkmcnt(0)" ::: "memory"); \
  __builtin_amdgcn_sched_barrier(0); } while (0)
#define VMWN() do { if constexpr (MFR == 8) \
    asm volatile("s_waitcnt vmcnt(4)" ::: "memory"); \
  else asm volatile("s_waitcnt vmcnt(2)" ::: "memory"); \
  __builtin_amdgcn_sched_barrier(0); } while (0)

#define RDA_(dst, mbase, dbuf) do { \
  char* _b = smem + (dbuf) * DBUF; \
  _Pragma("unroll") for (int mm = 0; mm < MFRH; ++mm) { \
    int _row = wr * (BM / 2) + ((mbase) + mm) * 16 + r15; \
    _Pragma("unroll") for (int ks = 0; ks < 2; ++ks) \
      dst[mm][ks] = *(const bfrag8*)(_b + _row * 128 + \
                                     (((g + ks * 4) ^ (_row & 7)) << 4)); \
  } } while (0)

#define RDB_(dst, nbase, dbuf) do { \
  char* _b = smem + (dbuf) * DBUF + AREG; \
  _Pragma("unroll") for (int nn = 0; nn < 2; ++nn) { \
    int _row = wc * 64 + ((nbase) + nn) * 16 + r15; \
    _Pragma("unroll") for (int ks = 0; ks < 2; ++ks) \
      dst[nn][ks] = *(const bfrag8*)(_b + _row * 128 + \
                                     (((g + ks * 4) ^ (_row & 7)) << 4)); \
  } } while (0)

#define MF_(a, b, mo, no) do { \
  __builtin_amdgcn_s_setprio(1); \
  _Pragma("unroll") for (int mm = 0; mm < MFRH; ++mm) \
  _Pragma("unroll") for (int nn = 0; nn < 2; ++nn) \
  _Pragma("unroll") for (int ks = 0; ks < 2; ++ks) \
    acc[(mo) + mm][(no) + nn] = __builtin_amdgcn_mfma_f32_16x16x32_bf16( \
        a[mm][ks], b[nn][ks], acc[(mo) + mm][(no) + nn], 0, 0, 0); \
  __builtin_amdgcn_s_setprio(0); \
} while (0)

enum { EP_PROJ = 0, EP_EXPERT = 1, EP_CTX = 2, EP_RELU = 3, EP_OUT = 4 };

// Grid: (N/256, M/BM). K%64==0, K/64 even >=2. A rows %BM==0, Bt rows %256==0.
template<int EP, int MFR>
__global__ __launch_bounds__(512, 2)
void gemm8(const u16* __restrict__ A, const u16* __restrict__ Bt,
           const float* __restrict__ bias, void* __restrict__ Cp,
           const float* __restrict__ gate, float* __restrict__ partials,
           int K, int lda, int ldb, int ldc, int nvalid)
{
  constexpr int MFRH = MFR / 2;
  constexpr int BM = MFR * 32;           // 256 or 128
  constexpr int AHALF = MFR * 2048;      // bytes per A half-tile
  constexpr int AREG = MFR * 4096;       // A region per dbuf
  constexpr int DBUF = AREG + 32768;     // dbuf stride (A + B regions)

  extern __shared__ char smem[];
  const int t = threadIdx.x;
  const int lane = t & 63, wid = t >> 6;
  const int wr = wid >> 2, wc = wid & 3;
  const int g = lane >> 4, r15 = lane & 15;

  // bijective XCD swizzle (nblk % 8 == 0 for all our grids)
  const int nblk = gridDim.x * gridDim.y;
  const int flat = blockIdx.y * gridDim.x + blockIdx.x;
  const int swz = (flat & 7) * (nblk >> 3) + (flat >> 3);
  const int bx = swz % gridDim.x, by = swz / gridDim.x;

  const long a0 = (long)(by * BM) * lda;
  const long b0 = (long)(bx * 256) * ldb;

  facc4 acc[MFR][4];
#pragma unroll
  for (int m = 0; m < MFR; m++)
#pragma unroll
    for (int n = 0; n < 4; n++) acc[m][n] = (facc4){0.f, 0.f, 0.f, 0.f};

  const int r0 = t >> 3, c0s = t & 7;
  const int csw = ((c0s ^ (r0 & 7)) << 3);   // swizzled k-chunk (elems)

  // which: 0=A-half0, 1=A-half1, 2=B-half0, 3=B-half1
  auto STAGE = [&](int kt, int which, int dbuf) {
    const int half = which & 1;
    if (which < 2) {
      char* ldst = smem + dbuf * DBUF + half * AHALF;
      const u16* gsrc =
          A + a0 + (long)(half * (BM / 2) + r0) * lda + kt * 64 + csw;
      gload16(gsrc, ldst + (t << 4));
      if (MFR == 8) gload16(gsrc + 64L * lda, ldst + ((512 + t) << 4));
    } else {
      char* ldst = smem + dbuf * DBUF + AREG + half * 16384;
      const u16* gsrc =
          Bt + b0 + (long)(half * 128 + r0) * ldb + kt * 64 + csw;
      gload16(gsrc, ldst + (t << 4));
      gload16(gsrc + 64L * ldb, ldst + ((512 + t) << 4));
    }
  };

  const int NT = K >> 6;
  STAGE(0, 0, 0); STAGE(0, 1, 0); STAGE(0, 2, 0); STAGE(0, 3, 0);
  STAGE(1, 0, 1); STAGE(1, 1, 1);
  VMWN(); BARX();

  bfrag8 aE[MFRH][2], aO[MFRH][2], b01[2][2], b23[2][2];

  for (int it = 0; it < (NT >> 1); ++it) {
    const int T = 2 * it;
    const int tp1 = T + 1;
    const int tp2 = (T + 2 < NT) ? T + 2 : NT - 1;
    const int tp3 = (T + 3 < NT) ? T + 3 : NT - 1;
    // P1: read (aE,b01) from buf0(T); stage (T+1).B0 -> buf1
    RDA_(aE, 0, 0); RDB_(b01, 0, 0); STAGE(tp1, 2, 1);
    LGKM0(); MF_(aE, b01, 0, 0); BARX();
    // P2: read aO; stage (T+1).B1
    RDA_(aO, MFRH, 0); STAGE(tp1, 3, 1);
    LGKM0(); MF_(aO, b01, MFRH, 0); BARX();
    // P3: read b23; stage (T+2).A -> buf0; MFMAs; drain so buf1(T+1) ready
    RDB_(b23, 2, 0); STAGE(tp2, 0, 0); STAGE(tp2, 1, 0);
    LGKM0(); MF_(aO, b23, MFRH, 2); MF_(aE, b23, 0, 2);
    VMWN(); BARX();
    // P4: read (aE,b01) from buf1(T+1); stage (T+2).B0 -> buf0
    RDA_(aE, 0, 1); RDB_(b01, 0, 1); STAGE(tp2, 2, 0);
    LGKM0(); MF_(aE, b01, 0, 0); BARX();
    // P5: read aO; stage (T+2).B1
    RDA_(aO, MFRH, 1); STAGE(tp2, 3, 0);
    LGKM0(); MF_(aO, b01, MFRH, 0); BARX();
    // P6: read b23; stage (T+3).A -> buf1; MFMAs; drain so buf0(T+2) ready
    RDB_(b23, 2, 1); STAGE(tp3, 0, 1); STAGE(tp3, 1, 1);
    LGKM0(); MF_(aO, b23, MFRH, 2); MF_(aE, b23, 0, 2);
    VMWN(); BARX();
  }

  // ---- epilogue: drain prefetches (they alias slab space), then LDS restage.
  asm volatile("s_waitcnt vmcnt(0)" ::: "memory");
  __builtin_amdgcn_sched_barrier(0);
  __builtin_amdgcn_s_barrier();
  __builtin_amdgcn_sched_barrier(0);

  const int rbase = by * BM + wr * (BM / 2);
  const int cbase = bx * 256 + wc * 64;
  float* slab = (float*)(smem + wid * 8704);   // per-wave [32][68] f32

  float psum[MFR][4];
  if (EP == EP_PROJ) {
#pragma unroll
    for (int m = 0; m < MFR; m++)
#pragma unroll
      for (int r = 0; r < 4; r++) psum[m][r] = 0.f;
  }

#pragma unroll
  for (int pass = 0; pass < MFRH; ++pass) {
#pragma unroll
    for (int mm = 0; mm < 2; ++mm) {
      const int m = pass * 2 + mm;
#pragma unroll
      for (int n = 0; n < 4; ++n)
#pragma unroll
        for (int r = 0; r < 4; ++r) {
          const int rowp = mm * 16 + g * 4 + r;
          const int grow = rbase + m * 16 + g * 4 + r;
          const int gcol = cbase + n * 16 + r15;
          float val = acc[m][n][r] + bias[gcol];
          if (EP == EP_EXPERT)
            val = fmaxf(val, 0.f) * gate[(long)grow * 16 + (gcol >> 7)];
          if (EP == EP_CTX && gcol < 20) val *= 2.0f;   // spiking attention
          if (EP == EP_RELU) val = fmaxf(val, 0.f);
          if (EP == EP_PROJ) psum[m][r] += val;
          slab[rowp * 68 + n * 16 + r15] = val;
        }
    }
    // wave-private slab; DS ops in-order within a wave (compiler inserts waits)
#pragma unroll
    for (int rep = 0; rep < 4; ++rep) {
      const int rowp = rep * 8 + (lane >> 3);
      const int cc = (lane & 7) * 8;
      const facc4 v0 = *(const facc4*)&slab[rowp * 68 + cc];
      const facc4 v1 = *(const facc4*)&slab[rowp * 68 + cc + 4];
      const long grow = rbase + pass * 32 + rowp;
      const int gcol0 = cbase + cc;
      if (EP == EP_OUT) {
        float* Cf = (float*)Cp;
        if (gcol0 + 7 < nvalid) {
          *(facc4*)(Cf + grow * ldc + gcol0) = v0;
          *(facc4*)(Cf + grow * ldc + gcol0 + 4) = v1;
        } else {
#pragma unroll
          for (int j = 0; j < 4; ++j)
            if (gcol0 + j < nvalid) Cf[grow * ldc + gcol0 + j] = v0[j];
#pragma unroll
          for (int j = 0; j < 4; ++j)
            if (gcol0 + 4 + j < nvalid) Cf[grow * ldc + gcol0 + 4 + j] = v1[j];
        }
      } else {
        u16 o[8];
        o[0] = f2bf(v0[0]); o[1] = f2bf(v0[1]);
        o[2] = f2bf(v0[2]); o[3] = f2bf(v0[3]);
        o[4] = f2bf(v1[0]); o[5] = f2bf(v1[1]);
        o[6] = f2bf(v1[2]); o[7] = f2bf(v1[3]);
        *(uint4*)((u16*)Cp + grow * ldc + gcol0) = *(const uint4*)o;
      }
    }
  }

  if (EP == EP_PROJ) {
#pragma unroll
    for (int m = 0; m < MFR; m++)
#pragma unroll
      for (int r = 0; r < 4; r++) {
        float p = psum[m][r];
        p += __shfl_xor(p, 1); p += __shfl_xor(p, 2);
        p += __shfl_xor(p, 4); p += __shfl_xor(p, 8);
        if (r15 == 0)
          partials[(long)(rbase + m * 16 + g * 4 + r) * 32 + bx * 4 + wc] = p;
      }
  }
}

// out[n][k] = bf16(in[k][n]); pads rows n>=N with zeros. Grid: (ceil(N/64), K/64, Z).
__global__ __launch_bounds__(256)
void transpose_conv_k(const float* __restrict__ in, u16* __restrict__ out,
                      int K, int N, int ldout, long in_zstride, int out_zrows)
{
  __shared__ float tile[64][65];
  const int t = threadIdx.x;
  const int n0 = blockIdx.x * 64, k0 = blockIdx.y * 64;
  const float* src = in + (long)blockIdx.z * in_zstride;
  const int rr = t >> 4;
  const int cc = (t & 15) * 4;
#pragma unroll
  for (int j = 0; j < 4; j++) {
    int k = k0 + j * 16 + rr;
    int n = n0 + cc;
    float v0 = 0.f, v1 = 0.f, v2 = 0.f, v3 = 0.f;
    if (n + 3 < N) {
      facc4 v = *(const facc4*)(src + (long)k * N + n);
      v0 = v[0]; v1 = v[1]; v2 = v[2]; v3 = v[3];
    } else {
      if (n < N)     v0 = src[(long)k * N + n];
      if (n + 1 < N) v1 = src[(long)k * N + n + 1];
      if (n + 2 < N) v2 = src[(long)k * N + n + 2];
      if (n + 3 < N) v3 = src[(long)k * N + n + 3];
    }
    float* trow = &tile[j * 16 + rr][cc];
    trow[0] = v0; trow[1] = v1; trow[2] = v2; trow[3] = v3;
  }
  __syncthreads();
  const int n_l = t >> 2;
  const int kc = (t & 3) * 16;
  const int n_gl = n0 + n_l;
  u16 o16[16];
  const bool valid = n_gl < N;
#pragma unroll
  for (int i = 0; i < 16; i++) o16[i] = valid ? f2bf(tile[kc + i][n_l]) : (u16)0;
  long orow = (long)blockIdx.z * out_zrows + n_gl;
  u16* dst = out + orow * (long)ldout + k0 + kc;
  *(uint4*)dst = ((const uint4*)o16)[0];
  *(uint4*)(dst + 8) = ((const uint4*)o16)[1];
}

__global__ __launch_bounds__(256)
void f32_to_bf16_k(const float* __restrict__ in, u16* __restrict__ out)
{
  const long i = ((long)blockIdx.x * 256 + threadIdx.x) * 8;
  facc4 v0 = *(const facc4*)(in + i);
  facc4 v1 = *(const facc4*)(in + i + 4);
  u16 o[8];
  o[0] = f2bf(v0[0]); o[1] = f2bf(v0[1]); o[2] = f2bf(v0[2]); o[3] = f2bf(v0[3]);
  o[4] = f2bf(v1[0]); o[5] = f2bf(v1[1]); o[6] = f2bf(v1[2]); o[7] = f2bf(v1[3]);
  *(uint4*)(out + i) = *(const uint4*)o;
}

__global__ __launch_bounds__(128)
void temporal_k(const float* __restrict__ partials, u16* __restrict__ enh)
{
  __shared__ float tsh;
  const int b = blockIdx.x;
  const int j = threadIdx.x;  // 128
  if (j < 32) {
    float p = partials[(long)b * 32 + j];
    p += __shfl_xor(p, 1); p += __shfl_xor(p, 2); p += __shfl_xor(p, 4);
    p += __shfl_xor(p, 8); p += __shfl_xor(p, 16);
    if (j == 0) tsh = p;
  }
  __syncthreads();
  float tmean = tsh * (1.0f / 2048.0f);
  float v;
  if (j < 64) v = sinf(7.0f * tmean * (float)(j + 1));
  else        v = cosf(7.0f * tmean * (float)(j - 63));
  enh[(long)b * 2176 + 2048 + j] = f2bf(v);
}

// gate = softmax(enh @ Wg + bg); 8 rows/block staged in LDS once.
__global__ __launch_bounds__(128)
void gate_k(const u16* __restrict__ enh, const float* __restrict__ Wg,
            const float* __restrict__ bg, float* __restrict__ gate)
{
  __shared__ u16 lds[8][2184];   // +8 pad: banks spread
  const int t = threadIdx.x;
  const long row0 = (long)blockIdx.x * 8;
#pragma unroll
  for (int r8 = 0; r8 < 8; ++r8) {
    const u16* src = enh + (row0 + r8) * 2176;
    u16* dst = &lds[r8][0];
    *(uint4*)(dst + t * 8) = *(const uint4*)(src + t * 8);
    *(uint4*)(dst + (128 + t) * 8) = *(const uint4*)(src + (128 + t) * 8);
    if (t < 16)
      *(uint4*)(dst + (256 + t) * 8) = *(const uint4*)(src + (256 + t) * 8);
  }
  __syncthreads();
  const int r = t >> 4, e = t & 15;
  float acc = bg[e];
  for (int k = 0; k < 2176; k += 8) {
    uint4 a = *(const uint4*)&lds[r][k];
    const u16* ap = (const u16*)&a;
#pragma unroll
    for (int j = 0; j < 8; ++j)
      acc += bf2f(ap[j]) * Wg[(k + j) * 16 + e];
  }
  float mx = acc;
  mx = fmaxf(mx, __shfl_xor(mx, 8)); mx = fmaxf(mx, __shfl_xor(mx, 4));
  mx = fmaxf(mx, __shfl_xor(mx, 2)); mx = fmaxf(mx, __shfl_xor(mx, 1));
  float ex = expf(acc - mx);
  float sum = ex;
  sum += __shfl_xor(sum, 8); sum += __shfl_xor(sum, 4);
  sum += __shfl_xor(sum, 2); sum += __shfl_xor(sum, 1);
  gate[(row0 + r) * 16 + e] = ex / sum;
}

// comb[b][k] = sum_e expw[b][e*128+k], 8 k's per thread
__global__ __launch_bounds__(256)
void combine_k(const u16* __restrict__ expw, u16* __restrict__ comb)
{
  const long i = ((long)blockIdx.x * 256 + threadIdx.x) * 8;
  const long b = i >> 7;
  const int k = (int)(i & 127);
  float s[8] = {0.f, 0.f, 0.f, 0.f, 0.f, 0.f, 0.f, 0.f};
#pragma unroll
  for (int e = 0; e < 16; ++e) {
    uint4 v = *(const uint4*)(expw + b * 2048 + e * 128 + k);
    const u16* vp = (const u16*)&v;
#pragma unroll
    for (int j = 0; j < 8; ++j) s[j] += bf2f(vp[j]);
  }
  u16 o[8];
#pragma unroll
  for (int j = 0; j < 8; ++j) o[j] = f2bf(s[j]);
  *(uint4*)(comb + i) = *(const uint4*)o;
}

extern "C" void kernel_launch(void* const* d_in, const int* in_sizes, int n_in,
                              void* d_out, int out_size, void* d_ws,
                              size_t ws_size, hipStream_t stream)
{
  const float* x    = (const float*)d_in[0];
  const float* W_in = (const float*)d_in[1];
  const float* b_in = (const float*)d_in[2];
  const float* Wg   = (const float*)d_in[3];
  const float* bg   = (const float*)d_in[4];
  const float* We   = (const float*)d_in[5];
  const float* be   = (const float*)d_in[6];
  const float* Wo   = (const float*)d_in[7];
  const float* bo   = (const float*)d_in[8];
  const float* Wh   = (const float*)d_in[9];
  const float* bh   = (const float*)d_in[10];
  const float* Wcls = (const float*)d_in[11];
  const float* bcls = (const float*)d_in[12];
  float* out = (float*)d_out;

  char* ws = (char*)d_ws;
  u16* enhb   = (u16*)(ws);                    // 35,651,584  [8192][2176]
  u16* bufF   = (u16*)(ws + 35651584);         // 33,554,432  Wt_in+xb -> expw/h1/h3
  u16* bufA   = (u16*)(ws + 69206016);         //  8,912,896  Wt_e -> Wt_cls
  u16* Wt_o   = (u16*)(ws + 78118912);         //    524,288  [2048][128]
  u16* bufW1  = (u16*)(ws + 78643200);         //  8,388,608  Wh0 -> Wh2
  u16* bufW2  = (u16*)(ws + 87031808);         //  8,388,608  Wh1
  u16* comb   = (u16*)(ws + 95420416);         //  2,097,152  [8192][128]
  float* partials = (float*)(ws + 97517568);   //  1,048,576
  float* gate     = (float*)(ws + 98566144);   //    524,288
  u16* Wt_in  = bufF;                          // [2048][1024], dead after proj
  u16* xb     = bufF + 2097152;                // [8192][1024] bf16, dead after proj
  u16* Wt_e   = bufA;                          // [2048][2176], dead after expert
  u16* Wt_cls = bufA;                          // [1024][2048]

  hipFuncSetAttribute((const void*)gemm8<EP_PROJ, 8>,
                      hipFuncAttributeMaxDynamicSharedMemorySize, 131072);
  hipFuncSetAttribute((const void*)gemm8<EP_EXPERT, 8>,
                      hipFuncAttributeMaxDynamicSharedMemorySize, 131072);
  hipFuncSetAttribute((const void*)gemm8<EP_CTX, 8>,
                      hipFuncAttributeMaxDynamicSharedMemorySize, 131072);
  hipFuncSetAttribute((const void*)gemm8<EP_RELU, 8>,
                      hipFuncAttributeMaxDynamicSharedMemorySize, 131072);
  hipFuncSetAttribute((const void*)gemm8<EP_OUT, 4>,
                      hipFuncAttributeMaxDynamicSharedMemorySize, 98304);

  // ---- conversions needed before the first GEMMs
  f32_to_bf16_k<<<4096, 256, 0, stream>>>(x, xb);
  transpose_conv_k<<<dim3(32, 16, 1), 256, 0, stream>>>(W_in, Wt_in, 1024, 2048, 1024, 0, 0);
  transpose_conv_k<<<dim3(2, 34, 16), 256, 0, stream>>>(We, Wt_e, 2176, 128, 2176, 2176L * 128L, 128);
  transpose_conv_k<<<dim3(32, 2, 1), 256, 0, stream>>>(Wo, Wt_o, 128, 2048, 128, 0, 0);
  // Wh0 -> bufW1, Wh1 -> bufW2 (contiguous): one z=2 launch
  transpose_conv_k<<<dim3(32, 32, 2), 256, 0, stream>>>(Wh, bufW1, 2048, 2048, 2048, 2048L * 2048L, 2048);

  // 1) proj = x @ W_in + b_in -> enhb[:, :2048] + row partial sums
  gemm8<EP_PROJ, 8><<<dim3(8, 32), 512, 131072, stream>>>(
      xb, Wt_in, b_in, (void*)enhb, nullptr, partials, 1024, 1024, 1024, 2176, 2048);
  // 2) phasor bank -> enhb[:, 2048:]
  temporal_k<<<8192, 128, 0, stream>>>(partials, enhb);
  // 3) softmax gate
  gate_k<<<1024, 128, 0, stream>>>(enhb, Wg, bg, gate);
  // 4) experts: relu(enh @ We + be) * gate
  gemm8<EP_EXPERT, 8><<<dim3(8, 32), 512, 131072, stream>>>(
      enhb, Wt_e, be, (void*)bufF, gate, nullptr, 2176, 2176, 2176, 2048, 2048);
  // Wt_e dead -> convert Wcls into bufA
  transpose_conv_k<<<dim3(16, 32, 1), 256, 0, stream>>>(Wcls, Wt_cls, 2048, 1000, 2048, 0, 0);
  // 5) combine experts
  combine_k<<<512, 256, 0, stream>>>(bufF, comb);
  // 6) context = comb @ Wo + bo, cols<20 doubled -> attended (enhb region)
  gemm8<EP_CTX, 8><<<dim3(8, 32), 512, 131072, stream>>>(
      comb, Wt_o, bo, (void*)enhb, nullptr, nullptr, 128, 128, 128, 2048, 2048);
  // 7) MLP: h1 -> bufF, h2 -> enhb, h3 -> bufF
  gemm8<EP_RELU, 8><<<dim3(8, 32), 512, 131072, stream>>>(
      enhb, bufW1, bh, (void*)bufF, nullptr, nullptr, 2048, 2048, 2048, 2048, 2048);
  transpose_conv_k<<<dim3(32, 32, 1), 256, 0, stream>>>(Wh + 2L * 2048L * 2048L, bufW1, 2048, 2048, 2048, 0, 0);
  gemm8<EP_RELU, 8><<<dim3(8, 32), 512, 131072, stream>>>(
      bufF, bufW2, bh + 2048, (void*)enhb, nullptr, nullptr, 2048, 2048, 2048, 2048, 2048);
  gemm8<EP_RELU, 8><<<dim3(8, 32), 512, 131072, stream>>>(
      enhb, bufW1, bh + 4096, (void*)bufF, nullptr, nullptr, 2048, 2048, 2048, 2048, 2048);
  // 8) logits: BM=128 variant, grid (4,64) = 256 blocks -> full CU utilization.
  //    (N=1000 -> padded 1024; Wt_cls rows >=1000 are zero; stores masked)
  gemm8<EP_OUT, 4><<<dim3(4, 64), 512, 98304, stream>>>(
      bufF, Wt_cls, bcls, (void*)out, nullptr, nullptr, 2048, 2048, 2048, 1000, 1000);
}

// Round 11
// 409.656 us; speedup vs baseline: 1.1777x; 1.0051x over previous
//
#include <hip/hip_runtime.h>
#include <math.h>

// ---------------------------------------------------------------------------
// SophisticatedBioInspiredModel — bf16 MFMA (16x16x32), 6-phase GEMMs (gfx950).
//
// Spiking attention is data-independent: 100 distinct tokens, each bumped once
// from decayed-zero -> v=1.0 < 1.2 -> no spikes -> counts==0 -> top_k(zeros,20)
// = indices 0..19 -> gains double cols 0..19 of context.
//
// GEMM: C = A(MxK,bf16) * Bt(NxK,bf16)^T. Template MFR = m-frags/wave:
//   MFR=8: 256x256 tile, 128 KiB LDS (measured-best r5 schedule)
//   MFR=4: 128x256 tile,  96 KiB LDS — for the N=1000 logits GEMM so the
//          grid is 256 blocks (full CU utilization) instead of 128.
// 6-phase / 2 K-tiles, counted vmcnt at P3/P6 (never 0 in loop). NOTE
// (r10 lesson): stage positions here are at each LDS region's EARLIEST-LEGAL
// point — b01/b23 read-unions each span BOTH B halves (P1 and P3), so B
// stages cannot move before P4 without a write-before-read race.
// chunk^(row&7) swizzle (conflict-free for 16x16 frags; 32x32 inherently
// 4-way-conflicted — r7), setprio, bijective XCD swizzle, LDS-restaged stores.
// ---------------------------------------------------------------------------

typedef unsigned short u16;
typedef __attribute__((ext_vector_type(8))) short bfrag8;
typedef __attribute__((ext_vector_type(4))) float facc4;

__device__ __forceinline__ u16 f2bf(float f) {
  union { float f; unsigned u; } c; c.f = f;
  unsigned u = c.u;
  return (u16)((u + 0x7fffu + ((u >> 16) & 1u)) >> 16);
}
__device__ __forceinline__ float bf2f(u16 h) {
  union { unsigned u; float f; } c; c.u = ((unsigned)h) << 16;
  return c.f;
}
__device__ __forceinline__ void gload16(const void* g, void* lds) {
  __builtin_amdgcn_global_load_lds(
      (const __attribute__((address_space(1))) unsigned*)g,
      (__attribute__((address_space(3))) unsigned*)lds, 16, 0, 0);
}

#define BARX() do { __builtin_amdgcn_sched_barrier(0); \
  __builtin_amdgcn_s_barrier(); __builtin_amdgcn_sched_barrier(0); } while (0)
#define LGKM0() do { asm volatile("s_waitcnt lgkmcnt(0)" ::: "memory"); \
  __builtin_amdgcn_sched_barrier(0); } while (0)
#define VMWN() do { if constexpr (MFR == 8) \
    asm volatile("s_waitcnt vmcnt(4)" ::: "memory"); \
  else asm volatile("s_waitcnt vmcnt(2)" ::: "memory"); \
  __builtin_amdgcn_sched_barrier(0); } while (0)

#define RDA_(dst, mbase, dbuf) do { \
  char* _b = smem + (dbuf) * DBUF; \
  _Pragma("unroll") for (int mm = 0; mm < MFRH; ++mm) { \
    int _row = wr * (BM / 2) + ((mbase) + mm) * 16 + r15; \
    _Pragma("unroll") for (int ks = 0; ks < 2; ++ks) \
      dst[mm][ks] = *(const bfrag8*)(_b + _row * 128 + \
                                     (((g + ks * 4) ^ (_row & 7)) << 4)); \
  } } while (0)

#define RDB_(dst, nbase, dbuf) do { \
  char* _b = smem + (dbuf) * DBUF + AREG; \
  _Pragma("unroll") for (int nn = 0; nn < 2; ++nn) { \
    int _row = wc * 64 + ((nbase) + nn) * 16 + r15; \
    _Pragma("unroll") for (int ks = 0; ks < 2; ++ks) \
      dst[nn][ks] = *(const bfrag8*)(_b + _row * 128 + \
                                     (((g + ks * 4) ^ (_row & 7)) << 4)); \
  } } while (0)

#define MF_(a, b, mo, no) do { \
  __builtin_amdgcn_s_setprio(1); \
  _Pragma("unroll") for (int mm = 0; mm < MFRH; ++mm) \
  _Pragma("unroll") for (int nn = 0; nn < 2; ++nn) \
  _Pragma("unroll") for (int ks = 0; ks < 2; ++ks) \
    acc[(mo) + mm][(no) + nn] = __builtin_amdgcn_mfma_f32_16x16x32_bf16( \
        a[mm][ks], b[nn][ks], acc[(mo) + mm][(no) + nn], 0, 0, 0); \
  __builtin_amdgcn_s_setprio(0); \
} while (0)

enum { EP_PROJ = 0, EP_EXPERT = 1, EP_CTX = 2, EP_RELU = 3, EP_OUT = 4 };

// Grid: (N/256, M/BM). K%64==0, K/64 even >=2. A rows %BM==0, Bt rows %256==0.
template<int EP, int MFR>
__global__ __launch_bounds__(512, 2)
void gemm8(const u16* __restrict__ A, const u16* __restrict__ Bt,
           const float* __restrict__ bias, void* __restrict__ Cp,
           const float* __restrict__ gate, float* __restrict__ partials,
           int K, int lda, int ldb, int ldc, int nvalid)
{
  constexpr int MFRH = MFR / 2;
  constexpr int BM = MFR * 32;           // 256 or 128
  constexpr int AHALF = MFR * 2048;      // bytes per A half-tile
  constexpr int AREG = MFR * 4096;       // A region per dbuf
  constexpr int DBUF = AREG + 32768;     // dbuf stride (A + B regions)

  extern __shared__ char smem[];
  const int t = threadIdx.x;
  const int lane = t & 63, wid = t >> 6;
  const int wr = wid >> 2, wc = wid & 3;
  const int g = lane >> 4, r15 = lane & 15;

  // bijective XCD swizzle (nblk % 8 == 0 for all our grids)
  const int nblk = gridDim.x * gridDim.y;
  const int flat = blockIdx.y * gridDim.x + blockIdx.x;
  const int swz = (flat & 7) * (nblk >> 3) + (flat >> 3);
  const int bx = swz % gridDim.x, by = swz / gridDim.x;

  const long a0 = (long)(by * BM) * lda;
  const long b0 = (long)(bx * 256) * ldb;

  facc4 acc[MFR][4];
#pragma unroll
  for (int m = 0; m < MFR; m++)
#pragma unroll
    for (int n = 0; n < 4; n++) acc[m][n] = (facc4){0.f, 0.f, 0.f, 0.f};

  const int r0 = t >> 3, c0s = t & 7;
  const int csw = ((c0s ^ (r0 & 7)) << 3);   // swizzled k-chunk (elems)

  // which: 0=A-half0, 1=A-half1, 2=B-half0, 3=B-half1
  auto STAGE = [&](int kt, int which, int dbuf) {
    const int half = which & 1;
    if (which < 2) {
      char* ldst = smem + dbuf * DBUF + half * AHALF;
      const u16* gsrc =
          A + a0 + (long)(half * (BM / 2) + r0) * lda + kt * 64 + csw;
      gload16(gsrc, ldst + (t << 4));
      if (MFR == 8) gload16(gsrc + 64L * lda, ldst + ((512 + t) << 4));
    } else {
      char* ldst = smem + dbuf * DBUF + AREG + half * 16384;
      const u16* gsrc =
          Bt + b0 + (long)(half * 128 + r0) * ldb + kt * 64 + csw;
      gload16(gsrc, ldst + (t << 4));
      gload16(gsrc + 64L * ldb, ldst + ((512 + t) << 4));
    }
  };

  const int NT = K >> 6;
  STAGE(0, 0, 0); STAGE(0, 1, 0); STAGE(0, 2, 0); STAGE(0, 3, 0);
  STAGE(1, 0, 1); STAGE(1, 1, 1);
  VMWN(); BARX();

  bfrag8 aE[MFRH][2], aO[MFRH][2], b01[2][2], b23[2][2];

  for (int it = 0; it < (NT >> 1); ++it) {
    const int T = 2 * it;
    const int tp1 = T + 1;
    const int tp2 = (T + 2 < NT) ? T + 2 : NT - 1;
    const int tp3 = (T + 3 < NT) ? T + 3 : NT - 1;
    // P1: read (aE,b01) from buf0(T); stage (T+1).B0 -> buf1
    RDA_(aE, 0, 0); RDB_(b01, 0, 0); STAGE(tp1, 2, 1);
    LGKM0(); MF_(aE, b01, 0, 0); BARX();
    // P2: read aO; stage (T+1).B1
    RDA_(aO, MFRH, 0); STAGE(tp1, 3, 1);
    LGKM0(); MF_(aO, b01, MFRH, 0); BARX();
    // P3: read b23; stage (T+2).A -> buf0; MFMAs; drain so buf1(T+1) ready
    RDB_(b23, 2, 0); STAGE(tp2, 0, 0); STAGE(tp2, 1, 0);
    LGKM0(); MF_(aO, b23, MFRH, 2); MF_(aE, b23, 0, 2);
    VMWN(); BARX();
    // P4: read (aE,b01) from buf1(T+1); stage (T+2).B0 -> buf0
    RDA_(aE, 0, 1); RDB_(b01, 0, 1); STAGE(tp2, 2, 0);
    LGKM0(); MF_(aE, b01, 0, 0); BARX();
    // P5: read aO; stage (T+2).B1
    RDA_(aO, MFRH, 1); STAGE(tp2, 3, 0);
    LGKM0(); MF_(aO, b01, MFRH, 0); BARX();
    // P6: read b23; stage (T+3).A -> buf1; MFMAs; drain so buf0(T+2) ready
    RDB_(b23, 2, 1); STAGE(tp3, 0, 1); STAGE(tp3, 1, 1);
    LGKM0(); MF_(aO, b23, MFRH, 2); MF_(aE, b23, 0, 2);
    VMWN(); BARX();
  }

  // ---- epilogue: drain prefetches (they alias slab space), then LDS restage.
  asm volatile("s_waitcnt vmcnt(0)" ::: "memory");
  __builtin_amdgcn_sched_barrier(0);
  __builtin_amdgcn_s_barrier();
  __builtin_amdgcn_sched_barrier(0);

  const int rbase = by * BM + wr * (BM / 2);
  const int cbase = bx * 256 + wc * 64;
  float* slab = (float*)(smem + wid * 8704);   // per-wave [32][68] f32

  float psum[MFR][4];
  if (EP == EP_PROJ) {
#pragma unroll
    for (int m = 0; m < MFR; m++)
#pragma unroll
      for (int r = 0; r < 4; r++) psum[m][r] = 0.f;
  }

#pragma unroll
  for (int pass = 0; pass < MFRH; ++pass) {
#pragma unroll
    for (int mm = 0; mm < 2; ++mm) {
      const int m = pass * 2 + mm;
#pragma unroll
      for (int n = 0; n < 4; ++n)
#pragma unroll
        for (int r = 0; r < 4; ++r) {
          const int rowp = mm * 16 + g * 4 + r;
          const int grow = rbase + m * 16 + g * 4 + r;
          const int gcol = cbase + n * 16 + r15;
          float val = acc[m][n][r] + bias[gcol];
          if (EP == EP_EXPERT)
            val = fmaxf(val, 0.f) * gate[(long)grow * 16 + (gcol >> 7)];
          if (EP == EP_CTX && gcol < 20) val *= 2.0f;   // spiking attention
          if (EP == EP_RELU) val = fmaxf(val, 0.f);
          if (EP == EP_PROJ) psum[m][r] += val;
          slab[rowp * 68 + n * 16 + r15] = val;
        }
    }
    // wave-private slab; DS ops in-order within a wave (compiler inserts waits)
#pragma unroll
    for (int rep = 0; rep < 4; ++rep) {
      const int rowp = rep * 8 + (lane >> 3);
      const int cc = (lane & 7) * 8;
      const facc4 v0 = *(const facc4*)&slab[rowp * 68 + cc];
      const facc4 v1 = *(const facc4*)&slab[rowp * 68 + cc + 4];
      const long grow = rbase + pass * 32 + rowp;
      const int gcol0 = cbase + cc;
      if (EP == EP_OUT) {
        float* Cf = (float*)Cp;
        if (gcol0 + 7 < nvalid) {
          *(facc4*)(Cf + grow * ldc + gcol0) = v0;
          *(facc4*)(Cf + grow * ldc + gcol0 + 4) = v1;
        } else {
#pragma unroll
          for (int j = 0; j < 4; ++j)
            if (gcol0 + j < nvalid) Cf[grow * ldc + gcol0 + j] = v0[j];
#pragma unroll
          for (int j = 0; j < 4; ++j)
            if (gcol0 + 4 + j < nvalid) Cf[grow * ldc + gcol0 + 4 + j] = v1[j];
        }
      } else {
        u16 o[8];
        o[0] = f2bf(v0[0]); o[1] = f2bf(v0[1]);
        o[2] = f2bf(v0[2]); o[3] = f2bf(v0[3]);
        o[4] = f2bf(v1[0]); o[5] = f2bf(v1[1]);
        o[6] = f2bf(v1[2]); o[7] = f2bf(v1[3]);
        *(uint4*)((u16*)Cp + grow * ldc + gcol0) = *(const uint4*)o;
      }
    }
  }

  if (EP == EP_PROJ) {
#pragma unroll
    for (int m = 0; m < MFR; m++)
#pragma unroll
      for (int r = 0; r < 4; r++) {
        float p = psum[m][r];
        p += __shfl_xor(p, 1); p += __shfl_xor(p, 2);
        p += __shfl_xor(p, 4); p += __shfl_xor(p, 8);
        if (r15 == 0)
          partials[(long)(rbase + m * 16 + g * 4 + r) * 32 + bx * 4 + wc] = p;
      }
  }
}

// out[n][k] = bf16(in[k][n]); pads rows n>=N with zeros. Grid: (ceil(N/64), K/64, Z).
__global__ __launch_bounds__(256)
void transpose_conv_k(const float* __restrict__ in, u16* __restrict__ out,
                      int K, int N, int ldout, long in_zstride, int out_zrows)
{
  __shared__ float tile[64][65];
  const int t = threadIdx.x;
  const int n0 = blockIdx.x * 64, k0 = blockIdx.y * 64;
  const float* src = in + (long)blockIdx.z * in_zstride;
  const int rr = t >> 4;
  const int cc = (t & 15) * 4;
#pragma unroll
  for (int j = 0; j < 4; j++) {
    int k = k0 + j * 16 + rr;
    int n = n0 + cc;
    float v0 = 0.f, v1 = 0.f, v2 = 0.f, v3 = 0.f;
    if (n + 3 < N) {
      facc4 v = *(const facc4*)(src + (long)k * N + n);
      v0 = v[0]; v1 = v[1]; v2 = v[2]; v3 = v[3];
    } else {
      if (n < N)     v0 = src[(long)k * N + n];
      if (n + 1 < N) v1 = src[(long)k * N + n + 1];
      if (n + 2 < N) v2 = src[(long)k * N + n + 2];
      if (n + 3 < N) v3 = src[(long)k * N + n + 3];
    }
    float* trow = &tile[j * 16 + rr][cc];
    trow[0] = v0; trow[1] = v1; trow[2] = v2; trow[3] = v3;
  }
  __syncthreads();
  const int n_l = t >> 2;
  const int kc = (t & 3) * 16;
  const int n_gl = n0 + n_l;
  u16 o16[16];
  const bool valid = n_gl < N;
#pragma unroll
  for (int i = 0; i < 16; i++) o16[i] = valid ? f2bf(tile[kc + i][n_l]) : (u16)0;
  long orow = (long)blockIdx.z * out_zrows + n_gl;
  u16* dst = out + orow * (long)ldout + k0 + kc;
  *(uint4*)dst = ((const uint4*)o16)[0];
  *(uint4*)(dst + 8) = ((const uint4*)o16)[1];
}

__global__ __launch_bounds__(256)
void f32_to_bf16_k(const float* __restrict__ in, u16* __restrict__ out)
{
  const long i = ((long)blockIdx.x * 256 + threadIdx.x) * 8;
  facc4 v0 = *(const facc4*)(in + i);
  facc4 v1 = *(const facc4*)(in + i + 4);
  u16 o[8];
  o[0] = f2bf(v0[0]); o[1] = f2bf(v0[1]); o[2] = f2bf(v0[2]); o[3] = f2bf(v0[3]);
  o[4] = f2bf(v1[0]); o[5] = f2bf(v1[1]); o[6] = f2bf(v1[2]); o[7] = f2bf(v1[3]);
  *(uint4*)(out + i) = *(const uint4*)o;
}

__global__ __launch_bounds__(128)
void temporal_k(const float* __restrict__ partials, u16* __restrict__ enh)
{
  __shared__ float tsh;
  const int b = blockIdx.x;
  const int j = threadIdx.x;  // 128
  if (j < 32) {
    float p = partials[(long)b * 32 + j];
    p += __shfl_xor(p, 1); p += __shfl_xor(p, 2); p += __shfl_xor(p, 4);
    p += __shfl_xor(p, 8); p += __shfl_xor(p, 16);
    if (j == 0) tsh = p;
  }
  __syncthreads();
  float tmean = tsh * (1.0f / 2048.0f);
  float v;
  if (j < 64) v = sinf(7.0f * tmean * (float)(j + 1));
  else        v = cosf(7.0f * tmean * (float)(j - 63));
  enh[(long)b * 2176 + 2048 + j] = f2bf(v);
}

// gate = softmax(enh @ Wg + bg); 8 rows/block staged in LDS once.
__global__ __launch_bounds__(128)
void gate_k(const u16* __restrict__ enh, const float* __restrict__ Wg,
            const float* __restrict__ bg, float* __restrict__ gate)
{
  __shared__ u16 lds[8][2184];   // +8 pad: banks spread
  const int t = threadIdx.x;
  const long row0 = (long)blockIdx.x * 8;
#pragma unroll
  for (int r8 = 0; r8 < 8; ++r8) {
    const u16* src = enh + (row0 + r8) * 2176;
    u16* dst = &lds[r8][0];
    *(uint4*)(dst + t * 8) = *(const uint4*)(src + t * 8);
    *(uint4*)(dst + (128 + t) * 8) = *(const uint4*)(src + (128 + t) * 8);
    if (t < 16)
      *(uint4*)(dst + (256 + t) * 8) = *(const uint4*)(src + (256 + t) * 8);
  }
  __syncthreads();
  const int r = t >> 4, e = t & 15;
  float acc = bg[e];
  for (int k = 0; k < 2176; k += 8) {
    uint4 a = *(const uint4*)&lds[r][k];
    const u16* ap = (const u16*)&a;
#pragma unroll
    for (int j = 0; j < 8; ++j)
      acc += bf2f(ap[j]) * Wg[(k + j) * 16 + e];
  }
  float mx = acc;
  mx = fmaxf(mx, __shfl_xor(mx, 8)); mx = fmaxf(mx, __shfl_xor(mx, 4));
  mx = fmaxf(mx, __shfl_xor(mx, 2)); mx = fmaxf(mx, __shfl_xor(mx, 1));
  float ex = expf(acc - mx);
  float sum = ex;
  sum += __shfl_xor(sum, 8); sum += __shfl_xor(sum, 4);
  sum += __shfl_xor(sum, 2); sum += __shfl_xor(sum, 1);
  gate[(row0 + r) * 16 + e] = ex / sum;
}

// comb[b][k] = sum_e expw[b][e*128+k], 8 k's per thread
__global__ __launch_bounds__(256)
void combine_k(const u16* __restrict__ expw, u16* __restrict__ comb)
{
  const long i = ((long)blockIdx.x * 256 + threadIdx.x) * 8;
  const long b = i >> 7;
  const int k = (int)(i & 127);
  float s[8] = {0.f, 0.f, 0.f, 0.f, 0.f, 0.f, 0.f, 0.f};
#pragma unroll
  for (int e = 0; e < 16; ++e) {
    uint4 v = *(const uint4*)(expw + b * 2048 + e * 128 + k);
    const u16* vp = (const u16*)&v;
#pragma unroll
    for (int j = 0; j < 8; ++j) s[j] += bf2f(vp[j]);
  }
  u16 o[8];
#pragma unroll
  for (int j = 0; j < 8; ++j) o[j] = f2bf(s[j]);
  *(uint4*)(comb + i) = *(const uint4*)o;
}

extern "C" void kernel_launch(void* const* d_in, const int* in_sizes, int n_in,
                              void* d_out, int out_size, void* d_ws,
                              size_t ws_size, hipStream_t stream)
{
  const float* x    = (const float*)d_in[0];
  const float* W_in = (const float*)d_in[1];
  const float* b_in = (const float*)d_in[2];
  const float* Wg   = (const float*)d_in[3];
  const float* bg   = (const float*)d_in[4];
  const float* We   = (const float*)d_in[5];
  const float* be   = (const float*)d_in[6];
  const float* Wo   = (const float*)d_in[7];
  const float* bo   = (const float*)d_in[8];
  const float* Wh   = (const float*)d_in[9];
  const float* bh   = (const float*)d_in[10];
  const float* Wcls = (const float*)d_in[11];
  const float* bcls = (const float*)d_in[12];
  float* out = (float*)d_out;

  char* ws = (char*)d_ws;
  u16* enhb   = (u16*)(ws);                    // 35,651,584  [8192][2176]
  u16* bufF   = (u16*)(ws + 35651584);         // 33,554,432  Wt_in+xb -> expw/h1/h3
  u16* bufA   = (u16*)(ws + 69206016);         //  8,912,896  Wt_e -> Wt_cls
  u16* Wt_o   = (u16*)(ws + 78118912);         //    524,288  [2048][128]
  u16* bufW1  = (u16*)(ws + 78643200);         //  8,388,608  Wh0 -> Wh2
  u16* bufW2  = (u16*)(ws + 87031808);         //  8,388,608  Wh1
  u16* comb   = (u16*)(ws + 95420416);         //  2,097,152  [8192][128]
  float* partials = (float*)(ws + 97517568);   //  1,048,576
  float* gate     = (float*)(ws + 98566144);   //    524,288
  u16* Wt_in  = bufF;                          // [2048][1024], dead after proj
  u16* xb     = bufF + 2097152;                // [8192][1024] bf16, dead after proj
  u16* Wt_e   = bufA;                          // [2048][2176], dead after expert
  u16* Wt_cls = bufA;                          // [1024][2048]

  hipFuncSetAttribute((const void*)gemm8<EP_PROJ, 8>,
                      hipFuncAttributeMaxDynamicSharedMemorySize, 131072);
  hipFuncSetAttribute((const void*)gemm8<EP_EXPERT, 8>,
                      hipFuncAttributeMaxDynamicSharedMemorySize, 131072);
  hipFuncSetAttribute((const void*)gemm8<EP_CTX, 8>,
                      hipFuncAttributeMaxDynamicSharedMemorySize, 131072);
  hipFuncSetAttribute((const void*)gemm8<EP_RELU, 8>,
                      hipFuncAttributeMaxDynamicSharedMemorySize, 131072);
  hipFuncSetAttribute((const void*)gemm8<EP_OUT, 4>,
                      hipFuncAttributeMaxDynamicSharedMemorySize, 98304);

  // ---- conversions needed before the first GEMMs
  f32_to_bf16_k<<<4096, 256, 0, stream>>>(x, xb);
  transpose_conv_k<<<dim3(32, 16, 1), 256, 0, stream>>>(W_in, Wt_in, 1024, 2048, 1024, 0, 0);
  transpose_conv_k<<<dim3(2, 34, 16), 256, 0, stream>>>(We, Wt_e, 2176, 128, 2176, 2176L * 128L, 128);
  transpose_conv_k<<<dim3(32, 2, 1), 256, 0, stream>>>(Wo, Wt_o, 128, 2048, 128, 0, 0);
  // Wh0 -> bufW1, Wh1 -> bufW2 (contiguous): one z=2 launch
  transpose_conv_k<<<dim3(32, 32, 2), 256, 0, stream>>>(Wh, bufW1, 2048, 2048, 2048, 2048L * 2048L, 2048);

  // 1) proj = x @ W_in + b_in -> enhb[:, :2048] + row partial sums
  gemm8<EP_PROJ, 8><<<dim3(8, 32), 512, 131072, stream>>>(
      xb, Wt_in, b_in, (void*)enhb, nullptr, partials, 1024, 1024, 1024, 2176, 2048);
  // 2) phasor bank -> enhb[:, 2048:]
  temporal_k<<<8192, 128, 0, stream>>>(partials, enhb);
  // 3) softmax gate
  gate_k<<<1024, 128, 0, stream>>>(enhb, Wg, bg, gate);
  // 4) experts: relu(enh @ We + be) * gate
  gemm8<EP_EXPERT, 8><<<dim3(8, 32), 512, 131072, stream>>>(
      enhb, Wt_e, be, (void*)bufF, gate, nullptr, 2176, 2176, 2176, 2048, 2048);
  // Wt_e dead -> convert Wcls into bufA
  transpose_conv_k<<<dim3(16, 32, 1), 256, 0, stream>>>(Wcls, Wt_cls, 2048, 1000, 2048, 0, 0);
  // 5) combine experts
  combine_k<<<512, 256, 0, stream>>>(bufF, comb);
  // 6) context = comb @ Wo + bo, cols<20 doubled -> attended (enhb region)
  gemm8<EP_CTX, 8><<<dim3(8, 32), 512, 131072, stream>>>(
      comb, Wt_o, bo, (void*)enhb, nullptr, nullptr, 128, 128, 128, 2048, 2048);
  // 7) MLP: h1 -> bufF, h2 -> enhb, h3 -> bufF
  gemm8<EP_RELU, 8><<<dim3(8, 32), 512, 131072, stream>>>(
      enhb, bufW1, bh, (void*)bufF, nullptr, nullptr, 2048, 2048, 2048, 2048, 2048);
  transpose_conv_k<<<dim3(32, 32, 1), 256, 0, stream>>>(Wh + 2L * 2048L * 2048L, bufW1, 2048, 2048, 2048, 0, 0);
  gemm8<EP_RELU, 8><<<dim3(8, 32), 512, 131072, stream>>>(
      bufF, bufW2, bh + 2048, (void*)enhb, nullptr, nullptr, 2048, 2048, 2048, 2048, 2048);
  gemm8<EP_RELU, 8><<<dim3(8, 32), 512, 131072, stream>>>(
      enhb, bufW1, bh + 4096, (void*)bufF, nullptr, nullptr, 2048, 2048, 2048, 2048, 2048);
  // 8) logits: BM=128 variant, grid (4,64) = 256 blocks -> full CU utilization.
  //    (N=1000 -> padded 1024; Wt_cls rows >=1000 are zero; stores masked)
  gemm8<EP_OUT, 4><<<dim3(4, 64), 512, 98304, stream>>>(
      bufF, Wt_cls, bcls, (void*)out, nullptr, nullptr, 2048, 2048, 2048, 1000, 1000);
}

// Round 12
// 377.112 us; speedup vs baseline: 1.2794x; 1.0863x over previous
//
#include <hip/hip_runtime.h>
#include <math.h>

// ---------------------------------------------------------------------------
// SophisticatedBioInspiredModel — bf16 MFMA (16x16x32), 6-phase GEMMs (gfx950).
//
// Spiking attention is data-independent: 100 distinct tokens, each bumped once
// from decayed-zero -> v=1.0 < 1.2 -> no spikes -> counts==0 -> top_k(zeros,20)
// = indices 0..19 -> gains double cols 0..19 of context.
//
// GEMM: C = A(MxK,bf16) * Bt(NxK,bf16)^T. Template MFR = m-frags/wave:
//   MFR=8: 256x256 tile, 128 KiB LDS;  MFR=4: 128x256, 96 KiB (logits GEMM,
//   grid 256 blocks -> full CU utilization).
// 6-phase / 2 K-tiles, counted vmcnt at P3/P6 (never 0 in loop). r10 lesson:
// stage positions are at each region's EARLIEST-LEGAL point (b01/b23 read-
// unions span BOTH B halves). chunk^(row&7) swizzle, setprio, XCD swizzle,
// LDS-restaged stores.
//
// r12: gate softmax rebuilt as MFMA (was serial-VALU, 67.5us at 0% MfmaUtil,
// 10x over its 6us stream roofline): one wave = 16 rows x 16 experts, K=2176,
// A direct-global (16 rows x 64B contiguous per frag load), B from bf16
// Wgt[16][2176] (L2-resident), softmax via shfl_xor in the C-frag layout.
// ---------------------------------------------------------------------------

typedef unsigned short u16;
typedef __attribute__((ext_vector_type(8))) short bfrag8;
typedef __attribute__((ext_vector_type(4))) float facc4;

__device__ __forceinline__ u16 f2bf(float f) {
  union { float f; unsigned u; } c; c.f = f;
  unsigned u = c.u;
  return (u16)((u + 0x7fffu + ((u >> 16) & 1u)) >> 16);
}
__device__ __forceinline__ float bf2f(u16 h) {
  union { unsigned u; float f; } c; c.u = ((unsigned)h) << 16;
  return c.f;
}
__device__ __forceinline__ void gload16(const void* g, void* lds) {
  __builtin_amdgcn_global_load_lds(
      (const __attribute__((address_space(1))) unsigned*)g,
      (__attribute__((address_space(3))) unsigned*)lds, 16, 0, 0);
}

#define BARX() do { __builtin_amdgcn_sched_barrier(0); \
  __builtin_amdgcn_s_barrier(); __builtin_amdgcn_sched_barrier(0); } while (0)
#define LGKM0() do { asm volatile("s_waitcnt lgkmcnt(0)" ::: "memory"); \
  __builtin_amdgcn_sched_barrier(0); } while (0)
#define VMWN() do { if constexpr (MFR == 8) \
    asm volatile("s_waitcnt vmcnt(4)" ::: "memory"); \
  else asm volatile("s_waitcnt vmcnt(2)" ::: "memory"); \
  __builtin_amdgcn_sched_barrier(0); } while (0)

#define RDA_(dst, mbase, dbuf) do { \
  char* _b = smem + (dbuf) * DBUF; \
  _Pragma("unroll") for (int mm = 0; mm < MFRH; ++mm) { \
    int _row = wr * (BM / 2) + ((mbase) + mm) * 16 + r15; \
    _Pragma("unroll") for (int ks = 0; ks < 2; ++ks) \
      dst[mm][ks] = *(const bfrag8*)(_b + _row * 128 + \
                                     (((g + ks * 4) ^ (_row & 7)) << 4)); \
  } } while (0)

#define RDB_(dst, nbase, dbuf) do { \
  char* _b = smem + (dbuf) * DBUF + AREG; \
  _Pragma("unroll") for (int nn = 0; nn < 2; ++nn) { \
    int _row = wc * 64 + ((nbase) + nn) * 16 + r15; \
    _Pragma("unroll") for (int ks = 0; ks < 2; ++ks) \
      dst[nn][ks] = *(const bfrag8*)(_b + _row * 128 + \
                                     (((g + ks * 4) ^ (_row & 7)) << 4)); \
  } } while (0)

#define MF_(a, b, mo, no) do { \
  __builtin_amdgcn_s_setprio(1); \
  _Pragma("unroll") for (int mm = 0; mm < MFRH; ++mm) \
  _Pragma("unroll") for (int nn = 0; nn < 2; ++nn) \
  _Pragma("unroll") for (int ks = 0; ks < 2; ++ks) \
    acc[(mo) + mm][(no) + nn] = __builtin_amdgcn_mfma_f32_16x16x32_bf16( \
        a[mm][ks], b[nn][ks], acc[(mo) + mm][(no) + nn], 0, 0, 0); \
  __builtin_amdgcn_s_setprio(0); \
} while (0)

enum { EP_PROJ = 0, EP_EXPERT = 1, EP_CTX = 2, EP_RELU = 3, EP_OUT = 4 };

// Grid: (N/256, M/BM). K%64==0, K/64 even >=2. A rows %BM==0, Bt rows %256==0.
template<int EP, int MFR>
__global__ __launch_bounds__(512, 2)
void gemm8(const u16* __restrict__ A, const u16* __restrict__ Bt,
           const float* __restrict__ bias, void* __restrict__ Cp,
           const float* __restrict__ gate, float* __restrict__ partials,
           int K, int lda, int ldb, int ldc, int nvalid)
{
  constexpr int MFRH = MFR / 2;
  constexpr int BM = MFR * 32;           // 256 or 128
  constexpr int AHALF = MFR * 2048;      // bytes per A half-tile
  constexpr int AREG = MFR * 4096;       // A region per dbuf
  constexpr int DBUF = AREG + 32768;     // dbuf stride (A + B regions)

  extern __shared__ char smem[];
  const int t = threadIdx.x;
  const int lane = t & 63, wid = t >> 6;
  const int wr = wid >> 2, wc = wid & 3;
  const int g = lane >> 4, r15 = lane & 15;

  // bijective XCD swizzle (nblk % 8 == 0 for all our grids)
  const int nblk = gridDim.x * gridDim.y;
  const int flat = blockIdx.y * gridDim.x + blockIdx.x;
  const int swz = (flat & 7) * (nblk >> 3) + (flat >> 3);
  const int bx = swz % gridDim.x, by = swz / gridDim.x;

  const long a0 = (long)(by * BM) * lda;
  const long b0 = (long)(bx * 256) * ldb;

  facc4 acc[MFR][4];
#pragma unroll
  for (int m = 0; m < MFR; m++)
#pragma unroll
    for (int n = 0; n < 4; n++) acc[m][n] = (facc4){0.f, 0.f, 0.f, 0.f};

  const int r0 = t >> 3, c0s = t & 7;
  const int csw = ((c0s ^ (r0 & 7)) << 3);   // swizzled k-chunk (elems)

  // which: 0=A-half0, 1=A-half1, 2=B-half0, 3=B-half1
  auto STAGE = [&](int kt, int which, int dbuf) {
    const int half = which & 1;
    if (which < 2) {
      char* ldst = smem + dbuf * DBUF + half * AHALF;
      const u16* gsrc =
          A + a0 + (long)(half * (BM / 2) + r0) * lda + kt * 64 + csw;
      gload16(gsrc, ldst + (t << 4));
      if (MFR == 8) gload16(gsrc + 64L * lda, ldst + ((512 + t) << 4));
    } else {
      char* ldst = smem + dbuf * DBUF + AREG + half * 16384;
      const u16* gsrc =
          Bt + b0 + (long)(half * 128 + r0) * ldb + kt * 64 + csw;
      gload16(gsrc, ldst + (t << 4));
      gload16(gsrc + 64L * ldb, ldst + ((512 + t) << 4));
    }
  };

  const int NT = K >> 6;
  STAGE(0, 0, 0); STAGE(0, 1, 0); STAGE(0, 2, 0); STAGE(0, 3, 0);
  STAGE(1, 0, 1); STAGE(1, 1, 1);
  VMWN(); BARX();

  bfrag8 aE[MFRH][2], aO[MFRH][2], b01[2][2], b23[2][2];

  for (int it = 0; it < (NT >> 1); ++it) {
    const int T = 2 * it;
    const int tp1 = T + 1;
    const int tp2 = (T + 2 < NT) ? T + 2 : NT - 1;
    const int tp3 = (T + 3 < NT) ? T + 3 : NT - 1;
    // P1: read (aE,b01) from buf0(T); stage (T+1).B0 -> buf1
    RDA_(aE, 0, 0); RDB_(b01, 0, 0); STAGE(tp1, 2, 1);
    LGKM0(); MF_(aE, b01, 0, 0); BARX();
    // P2: read aO; stage (T+1).B1
    RDA_(aO, MFRH, 0); STAGE(tp1, 3, 1);
    LGKM0(); MF_(aO, b01, MFRH, 0); BARX();
    // P3: read b23; stage (T+2).A -> buf0; MFMAs; drain so buf1(T+1) ready
    RDB_(b23, 2, 0); STAGE(tp2, 0, 0); STAGE(tp2, 1, 0);
    LGKM0(); MF_(aO, b23, MFRH, 2); MF_(aE, b23, 0, 2);
    VMWN(); BARX();
    // P4: read (aE,b01) from buf1(T+1); stage (T+2).B0 -> buf0
    RDA_(aE, 0, 1); RDB_(b01, 0, 1); STAGE(tp2, 2, 0);
    LGKM0(); MF_(aE, b01, 0, 0); BARX();
    // P5: read aO; stage (T+2).B1
    RDA_(aO, MFRH, 1); STAGE(tp2, 3, 0);
    LGKM0(); MF_(aO, b01, MFRH, 0); BARX();
    // P6: read b23; stage (T+3).A -> buf1; MFMAs; drain so buf0(T+2) ready
    RDB_(b23, 2, 1); STAGE(tp3, 0, 1); STAGE(tp3, 1, 1);
    LGKM0(); MF_(aO, b23, MFRH, 2); MF_(aE, b23, 0, 2);
    VMWN(); BARX();
  }

  // ---- epilogue: drain prefetches (they alias slab space), then LDS restage.
  asm volatile("s_waitcnt vmcnt(0)" ::: "memory");
  __builtin_amdgcn_sched_barrier(0);
  __builtin_amdgcn_s_barrier();
  __builtin_amdgcn_sched_barrier(0);

  const int rbase = by * BM + wr * (BM / 2);
  const int cbase = bx * 256 + wc * 64;
  float* slab = (float*)(smem + wid * 8704);   // per-wave [32][68] f32

  float psum[MFR][4];
  if (EP == EP_PROJ) {
#pragma unroll
    for (int m = 0; m < MFR; m++)
#pragma unroll
      for (int r = 0; r < 4; r++) psum[m][r] = 0.f;
  }

#pragma unroll
  for (int pass = 0; pass < MFRH; ++pass) {
#pragma unroll
    for (int mm = 0; mm < 2; ++mm) {
      const int m = pass * 2 + mm;
#pragma unroll
      for (int n = 0; n < 4; ++n)
#pragma unroll
        for (int r = 0; r < 4; ++r) {
          const int rowp = mm * 16 + g * 4 + r;
          const int grow = rbase + m * 16 + g * 4 + r;
          const int gcol = cbase + n * 16 + r15;
          float val = acc[m][n][r] + bias[gcol];
          if (EP == EP_EXPERT)
            val = fmaxf(val, 0.f) * gate[(long)grow * 16 + (gcol >> 7)];
          if (EP == EP_CTX && gcol < 20) val *= 2.0f;   // spiking attention
          if (EP == EP_RELU) val = fmaxf(val, 0.f);
          if (EP == EP_PROJ) psum[m][r] += val;
          slab[rowp * 68 + n * 16 + r15] = val;
        }
    }
    // wave-private slab; DS ops in-order within a wave (compiler inserts waits)
#pragma unroll
    for (int rep = 0; rep < 4; ++rep) {
      const int rowp = rep * 8 + (lane >> 3);
      const int cc = (lane & 7) * 8;
      const facc4 v0 = *(const facc4*)&slab[rowp * 68 + cc];
      const facc4 v1 = *(const facc4*)&slab[rowp * 68 + cc + 4];
      const long grow = rbase + pass * 32 + rowp;
      const int gcol0 = cbase + cc;
      if (EP == EP_OUT) {
        float* Cf = (float*)Cp;
        if (gcol0 + 7 < nvalid) {
          *(facc4*)(Cf + grow * ldc + gcol0) = v0;
          *(facc4*)(Cf + grow * ldc + gcol0 + 4) = v1;
        } else {
#pragma unroll
          for (int j = 0; j < 4; ++j)
            if (gcol0 + j < nvalid) Cf[grow * ldc + gcol0 + j] = v0[j];
#pragma unroll
          for (int j = 0; j < 4; ++j)
            if (gcol0 + 4 + j < nvalid) Cf[grow * ldc + gcol0 + 4 + j] = v1[j];
        }
      } else {
        u16 o[8];
        o[0] = f2bf(v0[0]); o[1] = f2bf(v0[1]);
        o[2] = f2bf(v0[2]); o[3] = f2bf(v0[3]);
        o[4] = f2bf(v1[0]); o[5] = f2bf(v1[1]);
        o[6] = f2bf(v1[2]); o[7] = f2bf(v1[3]);
        *(uint4*)((u16*)Cp + grow * ldc + gcol0) = *(const uint4*)o;
      }
    }
  }

  if (EP == EP_PROJ) {
#pragma unroll
    for (int m = 0; m < MFR; m++)
#pragma unroll
      for (int r = 0; r < 4; r++) {
        float p = psum[m][r];
        p += __shfl_xor(p, 1); p += __shfl_xor(p, 2);
        p += __shfl_xor(p, 4); p += __shfl_xor(p, 8);
        if (r15 == 0)
          partials[(long)(rbase + m * 16 + g * 4 + r) * 32 + bx * 4 + wc] = p;
      }
  }
}

// out[n][k] = bf16(in[k][n]); pads rows n>=N with zeros. Grid: (ceil(N/64), K/64, Z).
__global__ __launch_bounds__(256)
void transpose_conv_k(const float* __restrict__ in, u16* __restrict__ out,
                      int K, int N, int ldout, long in_zstride, int out_zrows)
{
  __shared__ float tile[64][65];
  const int t = threadIdx.x;
  const int n0 = blockIdx.x * 64, k0 = blockIdx.y * 64;
  const float* src = in + (long)blockIdx.z * in_zstride;
  const int rr = t >> 4;
  const int cc = (t & 15) * 4;
#pragma unroll
  for (int j = 0; j < 4; j++) {
    int k = k0 + j * 16 + rr;
    int n = n0 + cc;
    float v0 = 0.f, v1 = 0.f, v2 = 0.f, v3 = 0.f;
    if (n + 3 < N) {
      facc4 v = *(const facc4*)(src + (long)k * N + n);
      v0 = v[0]; v1 = v[1]; v2 = v[2]; v3 = v[3];
    } else {
      if (n < N)     v0 = src[(long)k * N + n];
      if (n + 1 < N) v1 = src[(long)k * N + n + 1];
      if (n + 2 < N) v2 = src[(long)k * N + n + 2];
      if (n + 3 < N) v3 = src[(long)k * N + n + 3];
    }
    float* trow = &tile[j * 16 + rr][cc];
    trow[0] = v0; trow[1] = v1; trow[2] = v2; trow[3] = v3;
  }
  __syncthreads();
  const int n_l = t >> 2;
  const int kc = (t & 3) * 16;
  const int n_gl = n0 + n_l;
  u16 o16[16];
  const bool valid = n_gl < N;
#pragma unroll
  for (int i = 0; i < 16; i++) o16[i] = valid ? f2bf(tile[kc + i][n_l]) : (u16)0;
  long orow = (long)blockIdx.z * out_zrows + n_gl;
  u16* dst = out + orow * (long)ldout + k0 + kc;
  *(uint4*)dst = ((const uint4*)o16)[0];
  *(uint4*)(dst + 8) = ((const uint4*)o16)[1];
}

__global__ __launch_bounds__(256)
void f32_to_bf16_k(const float* __restrict__ in, u16* __restrict__ out)
{
  const long i = ((long)blockIdx.x * 256 + threadIdx.x) * 8;
  facc4 v0 = *(const facc4*)(in + i);
  facc4 v1 = *(const facc4*)(in + i + 4);
  u16 o[8];
  o[0] = f2bf(v0[0]); o[1] = f2bf(v0[1]); o[2] = f2bf(v0[2]); o[3] = f2bf(v0[3]);
  o[4] = f2bf(v1[0]); o[5] = f2bf(v1[1]); o[6] = f2bf(v1[2]); o[7] = f2bf(v1[3]);
  *(uint4*)(out + i) = *(const uint4*)o;
}

__global__ __launch_bounds__(128)
void temporal_k(const float* __restrict__ partials, u16* __restrict__ enh)
{
  __shared__ float tsh;
  const int b = blockIdx.x;
  const int j = threadIdx.x;  // 128
  if (j < 32) {
    float p = partials[(long)b * 32 + j];
    p += __shfl_xor(p, 1); p += __shfl_xor(p, 2); p += __shfl_xor(p, 4);
    p += __shfl_xor(p, 8); p += __shfl_xor(p, 16);
    if (j == 0) tsh = p;
  }
  __syncthreads();
  float tmean = tsh * (1.0f / 2048.0f);
  float v;
  if (j < 64) v = sinf(7.0f * tmean * (float)(j + 1));
  else        v = cosf(7.0f * tmean * (float)(j - 63));
  enh[(long)b * 2176 + 2048 + j] = f2bf(v);
}

// gate = softmax(enh @ Wg + bg) via MFMA. One wave = 16 rows x 16 experts,
// K=2176. A direct from global (per frag-load: 16 rows x 64B contiguous),
// B from bf16 Wgt[16][2176] (L2-resident). Softmax across experts = shfl_xor
// {1,2,4,8} in the C-frag layout (col=lane&15=expert, row=(lane>>4)*4+reg).
// Grid: 512 blocks x 64 threads (1 wave, rows blockIdx*16 .. +15).
__global__ __launch_bounds__(64)
void gate2_k(const u16* __restrict__ enh, const u16* __restrict__ Wgt,
             const float* __restrict__ bg, float* __restrict__ gate)
{
  const int lane = threadIdx.x & 63;
  const int g = lane >> 4, r15 = lane & 15;
  const long rowbase = (long)blockIdx.x * 16;

  const u16* arow = enh + (rowbase + r15) * 2176 + g * 8;
  const u16* brow = Wgt + (long)r15 * 2176 + g * 8;

  facc4 acc = (facc4){0.f, 0.f, 0.f, 0.f};
#pragma unroll 4
  for (int kt = 0; kt < 2176; kt += 64) {
    bfrag8 a0 = *(const bfrag8*)(arow + kt);
    bfrag8 b0 = *(const bfrag8*)(brow + kt);
    bfrag8 a1 = *(const bfrag8*)(arow + kt + 32);
    bfrag8 b1 = *(const bfrag8*)(brow + kt + 32);
    acc = __builtin_amdgcn_mfma_f32_16x16x32_bf16(a0, b0, acc, 0, 0, 0);
    acc = __builtin_amdgcn_mfma_f32_16x16x32_bf16(a1, b1, acc, 0, 0, 0);
  }

  const float bb = bg[r15];
#pragma unroll
  for (int r = 0; r < 4; ++r) {
    float v = acc[r] + bb;
    float mx = v;
    mx = fmaxf(mx, __shfl_xor(mx, 1)); mx = fmaxf(mx, __shfl_xor(mx, 2));
    mx = fmaxf(mx, __shfl_xor(mx, 4)); mx = fmaxf(mx, __shfl_xor(mx, 8));
    float ex = expf(v - mx);
    float sum = ex;
    sum += __shfl_xor(sum, 1); sum += __shfl_xor(sum, 2);
    sum += __shfl_xor(sum, 4); sum += __shfl_xor(sum, 8);
    gate[(rowbase + g * 4 + r) * 16 + r15] = ex / sum;
  }
}

// comb[b][k] = sum_e expw[b][e*128+k], 8 k's per thread
__global__ __launch_bounds__(256)
void combine_k(const u16* __restrict__ expw, u16* __restrict__ comb)
{
  const long i = ((long)blockIdx.x * 256 + threadIdx.x) * 8;
  const long b = i >> 7;
  const int k = (int)(i & 127);
  float s[8] = {0.f, 0.f, 0.f, 0.f, 0.f, 0.f, 0.f, 0.f};
#pragma unroll
  for (int e = 0; e < 16; ++e) {
    uint4 v = *(const uint4*)(expw + b * 2048 + e * 128 + k);
    const u16* vp = (const u16*)&v;
#pragma unroll
    for (int j = 0; j < 8; ++j) s[j] += bf2f(vp[j]);
  }
  u16 o[8];
#pragma unroll
  for (int j = 0; j < 8; ++j) o[j] = f2bf(s[j]);
  *(uint4*)(comb + i) = *(const uint4*)o;
}

extern "C" void kernel_launch(void* const* d_in, const int* in_sizes, int n_in,
                              void* d_out, int out_size, void* d_ws,
                              size_t ws_size, hipStream_t stream)
{
  const float* x    = (const float*)d_in[0];
  const float* W_in = (const float*)d_in[1];
  const float* b_in = (const float*)d_in[2];
  const float* Wg   = (const float*)d_in[3];
  const float* bg   = (const float*)d_in[4];
  const float* We   = (const float*)d_in[5];
  const float* be   = (const float*)d_in[6];
  const float* Wo   = (const float*)d_in[7];
  const float* bo   = (const float*)d_in[8];
  const float* Wh   = (const float*)d_in[9];
  const float* bh   = (const float*)d_in[10];
  const float* Wcls = (const float*)d_in[11];
  const float* bcls = (const float*)d_in[12];
  float* out = (float*)d_out;

  char* ws = (char*)d_ws;
  u16* enhb   = (u16*)(ws);                    // 35,651,584  [8192][2176]
  u16* bufF   = (u16*)(ws + 35651584);         // 33,554,432  Wt_in+xb -> expw/h1/h3
  u16* bufA   = (u16*)(ws + 69206016);         //  8,912,896  Wt_e -> Wt_cls
  u16* Wt_o   = (u16*)(ws + 78118912);         //    524,288  [2048][128]
  u16* bufW1  = (u16*)(ws + 78643200);         //  8,388,608  Wh0 -> Wh2
  u16* bufW2  = (u16*)(ws + 87031808);         //  8,388,608  Wh1
  u16* comb   = (u16*)(ws + 95420416);         //  2,097,152  [8192][128]
  float* partials = (float*)(ws + 97517568);   //  1,048,576
  float* gate     = (float*)(ws + 98566144);   //    524,288
  u16* Wt_in  = bufF;                          // [2048][1024], dead after proj
  u16* xb     = bufF + 2097152;                // [8192][1024] bf16, dead after proj
  u16* Wgt    = bufF;                          // [64][2176] bf16, after proj (278KB)
  u16* Wt_e   = bufA;                          // [2048][2176], dead after expert
  u16* Wt_cls = bufA;                          // [1024][2048]

  hipFuncSetAttribute((const void*)gemm8<EP_PROJ, 8>,
                      hipFuncAttributeMaxDynamicSharedMemorySize, 131072);
  hipFuncSetAttribute((const void*)gemm8<EP_EXPERT, 8>,
                      hipFuncAttributeMaxDynamicSharedMemorySize, 131072);
  hipFuncSetAttribute((const void*)gemm8<EP_CTX, 8>,
                      hipFuncAttributeMaxDynamicSharedMemorySize, 131072);
  hipFuncSetAttribute((const void*)gemm8<EP_RELU, 8>,
                      hipFuncAttributeMaxDynamicSharedMemorySize, 131072);
  hipFuncSetAttribute((const void*)gemm8<EP_OUT, 4>,
                      hipFuncAttributeMaxDynamicSharedMemorySize, 98304);

  // ---- conversions needed before the first GEMMs
  f32_to_bf16_k<<<4096, 256, 0, stream>>>(x, xb);
  transpose_conv_k<<<dim3(32, 16, 1), 256, 0, stream>>>(W_in, Wt_in, 1024, 2048, 1024, 0, 0);
  transpose_conv_k<<<dim3(2, 34, 16), 256, 0, stream>>>(We, Wt_e, 2176, 128, 2176, 2176L * 128L, 128);
  transpose_conv_k<<<dim3(32, 2, 1), 256, 0, stream>>>(Wo, Wt_o, 128, 2048, 128, 0, 0);
  // Wh0 -> bufW1, Wh1 -> bufW2 (contiguous): one z=2 launch
  transpose_conv_k<<<dim3(32, 32, 2), 256, 0, stream>>>(Wh, bufW1, 2048, 2048, 2048, 2048L * 2048L, 2048);

  // 1) proj = x @ W_in + b_in -> enhb[:, :2048] + row partial sums
  gemm8<EP_PROJ, 8><<<dim3(8, 32), 512, 131072, stream>>>(
      xb, Wt_in, b_in, (void*)enhb, nullptr, partials, 1024, 1024, 1024, 2176, 2048);
  // 2) phasor bank -> enhb[:, 2048:]
  temporal_k<<<8192, 128, 0, stream>>>(partials, enhb);
  // Wt_in/xb dead -> transpose Wg into Wgt (bufF region) for the gate GEMM
  transpose_conv_k<<<dim3(1, 34, 1), 256, 0, stream>>>(Wg, Wgt, 2176, 16, 2176, 0, 0);
  // 3) softmax gate via MFMA
  gate2_k<<<512, 64, 0, stream>>>(enhb, Wgt, bg, gate);
  // 4) experts: relu(enh @ We + be) * gate
  gemm8<EP_EXPERT, 8><<<dim3(8, 32), 512, 131072, stream>>>(
      enhb, Wt_e, be, (void*)bufF, gate, nullptr, 2176, 2176, 2176, 2048, 2048);
  // Wt_e dead -> convert Wcls into bufA
  transpose_conv_k<<<dim3(16, 32, 1), 256, 0, stream>>>(Wcls, Wt_cls, 2048, 1000, 2048, 0, 0);
  // 5) combine experts
  combine_k<<<512, 256, 0, stream>>>(bufF, comb);
  // 6) context = comb @ Wo + bo, cols<20 doubled -> attended (enhb region)
  gemm8<EP_CTX, 8><<<dim3(8, 32), 512, 131072, stream>>>(
      comb, Wt_o, bo, (void*)enhb, nullptr, nullptr, 128, 128, 128, 2048, 2048);
  // 7) MLP: h1 -> bufF, h2 -> enhb, h3 -> bufF
  gemm8<EP_RELU, 8><<<dim3(8, 32), 512, 131072, stream>>>(
      enhb, bufW1, bh, (void*)bufF, nullptr, nullptr, 2048, 2048, 2048, 2048, 2048);
  transpose_conv_k<<<dim3(32, 32, 1), 256, 0, stream>>>(Wh + 2L * 2048L * 2048L, bufW1, 2048, 2048, 2048, 0, 0);
  gemm8<EP_RELU, 8><<<dim3(8, 32), 512, 131072, stream>>>(
      bufF, bufW2, bh + 2048, (void*)enhb, nullptr, nullptr, 2048, 2048, 2048, 2048, 2048);
  gemm8<EP_RELU, 8><<<dim3(8, 32), 512, 131072, stream>>>(
      enhb, bufW1, bh + 4096, (void*)bufF, nullptr, nullptr, 2048, 2048, 2048, 2048, 2048);
  // 8) logits: BM=128 variant, grid (4,64) = 256 blocks -> full CU utilization.
  //    (N=1000 -> padded 1024; Wt_cls rows >=1000 are zero; stores masked)
  gemm8<EP_OUT, 4><<<dim3(4, 64), 512, 98304, stream>>>(
      bufF, Wt_cls, bcls, (void*)out, nullptr, nullptr, 2048, 2048, 2048, 1000, 1000);
}

// Round 13
// 376.168 us; speedup vs baseline: 1.2826x; 1.0025x over previous
//
#include <hip/hip_runtime.h>
#include <math.h>

// ---------------------------------------------------------------------------
// SophisticatedBioInspiredModel — bf16 MFMA (16x16x32), 8-phase GEMMs (gfx950).
//
// Spiking attention is data-independent: 100 distinct tokens, each bumped once
// from decayed-zero -> v=1.0 < 1.2 -> no spikes -> counts==0 -> top_k(zeros,20)
// = indices 0..19 -> gains double cols 0..19 of context.
//
// GEMM: C = A(MxK,bf16) * Bt(NxK,bf16)^T. MFR=8: 256x256 tile, 128 KiB LDS;
// MFR=4: 128x256 (logits GEMM, 256 blocks -> full CU utilization).
//
// r13: B stored in LDS with PERMUTED row order: logical row r -> lds row
// ((r>>5)&1)*128 + ((r>>6)&3)*32 + (r&31), so half0 = exactly the b01-read
// rows, half1 = b23 rows. This unlocks a deep stage stagger (one half-tile
// stage per phase, issue->wait distance >=2 phases ~1200cy > HBM latency)
// that r10 proved illegal with linear row order. 8 phases / 2 K-tiles,
// counted vmcnt(4)/(3) at P4/P8 only. chunk^(row&7) swizzle (conflict-free
// for 16x16 frags), setprio, bijective XCD swizzle, LDS-restaged stores.
// ---------------------------------------------------------------------------

typedef unsigned short u16;
typedef __attribute__((ext_vector_type(8))) short bfrag8;
typedef __attribute__((ext_vector_type(4))) float facc4;

__device__ __forceinline__ u16 f2bf(float f) {
  union { float f; unsigned u; } c; c.f = f;
  unsigned u = c.u;
  return (u16)((u + 0x7fffu + ((u >> 16) & 1u)) >> 16);
}
__device__ __forceinline__ float bf2f(u16 h) {
  union { unsigned u; float f; } c; c.u = ((unsigned)h) << 16;
  return c.f;
}
__device__ __forceinline__ void gload16(const void* g, void* lds) {
  __builtin_amdgcn_global_load_lds(
      (const __attribute__((address_space(1))) unsigned*)g,
      (__attribute__((address_space(3))) unsigned*)lds, 16, 0, 0);
}

#define BARX() do { __builtin_amdgcn_sched_barrier(0); \
  __builtin_amdgcn_s_barrier(); __builtin_amdgcn_sched_barrier(0); } while (0)
#define LGKM0() do { asm volatile("s_waitcnt lgkmcnt(0)" ::: "memory"); \
  __builtin_amdgcn_sched_barrier(0); } while (0)
// counted drain; FIFO ledger: 6 stages outstanding, drain to 2 stages
#define VMWN() do { if constexpr (MFR == 8) \
    asm volatile("s_waitcnt vmcnt(4)" ::: "memory"); \
  else asm volatile("s_waitcnt vmcnt(3)" ::: "memory"); \
  __builtin_amdgcn_sched_barrier(0); } while (0)

#define RDA_(dst, mbase, dbuf) do { \
  char* _b = smem + (dbuf) * DBUF; \
  _Pragma("unroll") for (int mm = 0; mm < MFRH; ++mm) { \
    int _row = wr * (BM / 2) + ((mbase) + mm) * 16 + r15; \
    _Pragma("unroll") for (int ks = 0; ks < 2; ++ks) \
      dst[mm][ks] = *(const bfrag8*)(_b + _row * 128 + \
                                     (((g + ks * 4) ^ (_row & 7)) << 4)); \
  } } while (0)

// B reads from permuted layout: half = nbase>>1; lds row = wc*32 + nn*16 + r15
#define RDB_(dst, nbase, dbuf) do { \
  char* _b = smem + (dbuf) * DBUF + AREG + ((nbase) >> 1) * 16384; \
  _Pragma("unroll") for (int nn = 0; nn < 2; ++nn) { \
    int _row = wc * 32 + nn * 16 + r15; \
    _Pragma("unroll") for (int ks = 0; ks < 2; ++ks) \
      dst[nn][ks] = *(const bfrag8*)(_b + _row * 128 + \
                                     (((g + ks * 4) ^ (_row & 7)) << 4)); \
  } } while (0)

#define MF_(a, b, mo, no) do { \
  __builtin_amdgcn_s_setprio(1); \
  _Pragma("unroll") for (int mm = 0; mm < MFRH; ++mm) \
  _Pragma("unroll") for (int nn = 0; nn < 2; ++nn) \
  _Pragma("unroll") for (int ks = 0; ks < 2; ++ks) \
    acc[(mo) + mm][(no) + nn] = __builtin_amdgcn_mfma_f32_16x16x32_bf16( \
        a[mm][ks], b[nn][ks], acc[(mo) + mm][(no) + nn], 0, 0, 0); \
  __builtin_amdgcn_s_setprio(0); \
} while (0)

enum { EP_PROJ = 0, EP_EXPERT = 1, EP_CTX = 2, EP_RELU = 3, EP_OUT = 4 };

// Grid: (N/256, M/BM). K%64==0, K/64 even >=2. A rows %BM==0, Bt rows %256==0.
template<int EP, int MFR>
__global__ __launch_bounds__(512, 2)
void gemm8(const u16* __restrict__ A, const u16* __restrict__ Bt,
           const float* __restrict__ bias, void* __restrict__ Cp,
           const float* __restrict__ gate, float* __restrict__ partials,
           int K, int lda, int ldb, int ldc, int nvalid)
{
  constexpr int MFRH = MFR / 2;
  constexpr int BM = MFR * 32;           // 256 or 128
  constexpr int AHALF = MFR * 2048;      // bytes per A half-tile
  constexpr int AREG = MFR * 4096;       // A region per dbuf
  constexpr int DBUF = AREG + 32768;     // dbuf stride (A + B regions)

  extern __shared__ char smem[];
  const int t = threadIdx.x;
  const int lane = t & 63, wid = t >> 6;
  const int wr = wid >> 2, wc = wid & 3;
  const int g = lane >> 4, r15 = lane & 15;

  // bijective XCD swizzle (nblk % 8 == 0 for all our grids)
  const int nblk = gridDim.x * gridDim.y;
  const int flat = blockIdx.y * gridDim.x + blockIdx.x;
  const int swz = (flat & 7) * (nblk >> 3) + (flat >> 3);
  const int bx = swz % gridDim.x, by = swz / gridDim.x;

  const long a0 = (long)(by * BM) * lda;
  const long b0 = (long)(bx * 256) * ldb;

  facc4 acc[MFR][4];
#pragma unroll
  for (int m = 0; m < MFR; m++)
#pragma unroll
    for (int n = 0; n < 4; n++) acc[m][n] = (facc4){0.f, 0.f, 0.f, 0.f};

  const int r0 = t >> 3, c0s = t & 7;
  const int csw = ((c0s ^ (r0 & 7)) << 3);   // swizzled k-chunk (elems)
  // B permuted source row for lds row l=r0: logical = (l>>5)*64 + half*32 + (l&31)
  const int brow_base = (r0 >> 5) * 64 + (r0 & 31);

  // which: 0=A-half0, 1=A-half1, 2=B-half0, 3=B-half1
  auto STAGE = [&](int kt, int which, int dbuf) {
    const int half = which & 1;
    if (which < 2) {
      char* ldst = smem + dbuf * DBUF + half * AHALF;
      const u16* gsrc =
          A + a0 + (long)(half * (BM / 2) + r0) * lda + kt * 64 + csw;
      gload16(gsrc, ldst + (t << 4));
      if (MFR == 8) gload16(gsrc + 64L * lda, ldst + ((512 + t) << 4));
    } else {
      char* ldst = smem + dbuf * DBUF + AREG + half * 16384;
      const u16* gsrc =
          Bt + b0 + (long)(brow_base + half * 32) * ldb + kt * 64 + csw;
      gload16(gsrc, ldst + (t << 4));
      gload16(gsrc + 128L * ldb, ldst + ((512 + t) << 4));
    }
  };

  const int NT = K >> 6;
  // Prologue FIFO: B0(0),A0(0),A1(0),B1(0),B0(1),A0(1); drain tile0 -> leave 2.
  STAGE(0, 2, 0); STAGE(0, 0, 0); STAGE(0, 1, 0); STAGE(0, 3, 0);
  STAGE(1, 2, 1); STAGE(1, 0, 1);
  VMWN(); BARX();

  bfrag8 aE[MFRH][2], aO[MFRH][2], b01[2][2], b23[2][2];

  for (int it = 0; it < (NT >> 1); ++it) {
    const int T = 2 * it;
    const int tp1 = T + 1;
    const int tp2 = (T + 2 < NT) ? T + 2 : NT - 1;
    const int tp3 = (T + 3 < NT) ? T + 3 : NT - 1;
    // P1: read aE,b01 (buf0=T); stage (T+1).A1 -> buf1
    RDA_(aE, 0, 0); RDB_(b01, 0, 0); STAGE(tp1, 1, 1);
    LGKM0(); MF_(aE, b01, 0, 0); BARX();
    // P2: read aO; stage (T+1).B1 -> buf1 (B1(buf1) last read prev-P7)
    RDA_(aO, MFRH, 0); STAGE(tp1, 3, 1);
    LGKM0(); MF_(aO, b01, MFRH, 0); BARX();
    // P3: read b23; stage (T+2).B0 -> buf0 (B0(buf0)=b01 rows, read P1-P2)
    RDB_(b23, 2, 0); STAGE(tp2, 2, 0);
    LGKM0(); MF_(aO, b23, MFRH, 2); BARX();
    // P4: stage (T+2).A0 -> buf0 (A(buf0) read P1-P2); drain T+1 complete
    STAGE(tp2, 0, 0);
    MF_(aE, b23, 0, 2); VMWN(); BARX();
    // P5: read aE,b01 (buf1=T+1); stage (T+2).A1 -> buf0
    RDA_(aE, 0, 1); RDB_(b01, 0, 1); STAGE(tp2, 1, 0);
    LGKM0(); MF_(aE, b01, 0, 0); BARX();
    // P6: read aO; stage (T+2).B1 -> buf0 (B1(buf0) read P3-P4)
    RDA_(aO, MFRH, 1); STAGE(tp2, 3, 0);
    LGKM0(); MF_(aO, b01, MFRH, 0); BARX();
    // P7: read b23; stage (T+3).B0 -> buf1 (B0(buf1) read P5-P6)
    RDB_(b23, 2, 1); STAGE(tp3, 2, 1);
    LGKM0(); MF_(aO, b23, MFRH, 2); BARX();
    // P8: stage (T+3).A0 -> buf1 (A(buf1) read P5-P6); drain T+2 complete
    STAGE(tp3, 0, 1);
    MF_(aE, b23, 0, 2); VMWN(); BARX();
  }

  // ---- epilogue: drain prefetches (they alias slab space), then LDS restage.
  asm volatile("s_waitcnt vmcnt(0)" ::: "memory");
  __builtin_amdgcn_sched_barrier(0);
  __builtin_amdgcn_s_barrier();
  __builtin_amdgcn_sched_barrier(0);

  const int rbase = by * BM + wr * (BM / 2);
  const int cbase = bx * 256 + wc * 64;
  float* slab = (float*)(smem + wid * 8704);   // per-wave [32][68] f32

  float psum[MFR][4];
  if (EP == EP_PROJ) {
#pragma unroll
    for (int m = 0; m < MFR; m++)
#pragma unroll
      for (int r = 0; r < 4; r++) psum[m][r] = 0.f;
  }

#pragma unroll
  for (int pass = 0; pass < MFRH; ++pass) {
#pragma unroll
    for (int mm = 0; mm < 2; ++mm) {
      const int m = pass * 2 + mm;
#pragma unroll
      for (int n = 0; n < 4; ++n)
#pragma unroll
        for (int r = 0; r < 4; ++r) {
          const int rowp = mm * 16 + g * 4 + r;
          const int grow = rbase + m * 16 + g * 4 + r;
          const int gcol = cbase + n * 16 + r15;
          float val = acc[m][n][r] + bias[gcol];
          if (EP == EP_EXPERT)
            val = fmaxf(val, 0.f) * gate[(long)grow * 16 + (gcol >> 7)];
          if (EP == EP_CTX && gcol < 20) val *= 2.0f;   // spiking attention
          if (EP == EP_RELU) val = fmaxf(val, 0.f);
          if (EP == EP_PROJ) psum[m][r] += val;
          slab[rowp * 68 + n * 16 + r15] = val;
        }
    }
    // wave-private slab; DS ops in-order within a wave (compiler inserts waits)
#pragma unroll
    for (int rep = 0; rep < 4; ++rep) {
      const int rowp = rep * 8 + (lane >> 3);
      const int cc = (lane & 7) * 8;
      const facc4 v0 = *(const facc4*)&slab[rowp * 68 + cc];
      const facc4 v1 = *(const facc4*)&slab[rowp * 68 + cc + 4];
      const long grow = rbase + pass * 32 + rowp;
      const int gcol0 = cbase + cc;
      if (EP == EP_OUT) {
        float* Cf = (float*)Cp;
        if (gcol0 + 7 < nvalid) {
          *(facc4*)(Cf + grow * ldc + gcol0) = v0;
          *(facc4*)(Cf + grow * ldc + gcol0 + 4) = v1;
        } else {
#pragma unroll
          for (int j = 0; j < 4; ++j)
            if (gcol0 + j < nvalid) Cf[grow * ldc + gcol0 + j] = v0[j];
#pragma unroll
          for (int j = 0; j < 4; ++j)
            if (gcol0 + 4 + j < nvalid) Cf[grow * ldc + gcol0 + 4 + j] = v1[j];
        }
      } else {
        u16 o[8];
        o[0] = f2bf(v0[0]); o[1] = f2bf(v0[1]);
        o[2] = f2bf(v0[2]); o[3] = f2bf(v0[3]);
        o[4] = f2bf(v1[0]); o[5] = f2bf(v1[1]);
        o[6] = f2bf(v1[2]); o[7] = f2bf(v1[3]);
        *(uint4*)((u16*)Cp + grow * ldc + gcol0) = *(const uint4*)o;
      }
    }
  }

  if (EP == EP_PROJ) {
#pragma unroll
    for (int m = 0; m < MFR; m++)
#pragma unroll
      for (int r = 0; r < 4; r++) {
        float p = psum[m][r];
        p += __shfl_xor(p, 1); p += __shfl_xor(p, 2);
        p += __shfl_xor(p, 4); p += __shfl_xor(p, 8);
        if (r15 == 0)
          partials[(long)(rbase + m * 16 + g * 4 + r) * 32 + bx * 4 + wc] = p;
      }
  }
}

// out[n][k] = bf16(in[k][n]); pads rows n>=N with zeros. Grid: (ceil(N/64), K/64, Z).
__global__ __launch_bounds__(256)
void transpose_conv_k(const float* __restrict__ in, u16* __restrict__ out,
                      int K, int N, int ldout, long in_zstride, int out_zrows)
{
  __shared__ float tile[64][65];
  const int t = threadIdx.x;
  const int n0 = blockIdx.x * 64, k0 = blockIdx.y * 64;
  const float* src = in + (long)blockIdx.z * in_zstride;
  const int rr = t >> 4;
  const int cc = (t & 15) * 4;
#pragma unroll
  for (int j = 0; j < 4; j++) {
    int k = k0 + j * 16 + rr;
    int n = n0 + cc;
    float v0 = 0.f, v1 = 0.f, v2 = 0.f, v3 = 0.f;
    if (n + 3 < N) {
      facc4 v = *(const facc4*)(src + (long)k * N + n);
      v0 = v[0]; v1 = v[1]; v2 = v[2]; v3 = v[3];
    } else {
      if (n < N)     v0 = src[(long)k * N + n];
      if (n + 1 < N) v1 = src[(long)k * N + n + 1];
      if (n + 2 < N) v2 = src[(long)k * N + n + 2];
      if (n + 3 < N) v3 = src[(long)k * N + n + 3];
    }
    float* trow = &tile[j * 16 + rr][cc];
    trow[0] = v0; trow[1] = v1; trow[2] = v2; trow[3] = v3;
  }
  __syncthreads();
  const int n_l = t >> 2;
  const int kc = (t & 3) * 16;
  const int n_gl = n0 + n_l;
  u16 o16[16];
  const bool valid = n_gl < N;
#pragma unroll
  for (int i = 0; i < 16; i++) o16[i] = valid ? f2bf(tile[kc + i][n_l]) : (u16)0;
  long orow = (long)blockIdx.z * out_zrows + n_gl;
  u16* dst = out + orow * (long)ldout + k0 + kc;
  *(uint4*)dst = ((const uint4*)o16)[0];
  *(uint4*)(dst + 8) = ((const uint4*)o16)[1];
}

__global__ __launch_bounds__(256)
void f32_to_bf16_k(const float* __restrict__ in, u16* __restrict__ out)
{
  const long i = ((long)blockIdx.x * 256 + threadIdx.x) * 8;
  facc4 v0 = *(const facc4*)(in + i);
  facc4 v1 = *(const facc4*)(in + i + 4);
  u16 o[8];
  o[0] = f2bf(v0[0]); o[1] = f2bf(v0[1]); o[2] = f2bf(v0[2]); o[3] = f2bf(v0[3]);
  o[4] = f2bf(v1[0]); o[5] = f2bf(v1[1]); o[6] = f2bf(v1[2]); o[7] = f2bf(v1[3]);
  *(uint4*)(out + i) = *(const uint4*)o;
}

__global__ __launch_bounds__(128)
void temporal_k(const float* __restrict__ partials, u16* __restrict__ enh)
{
  __shared__ float tsh;
  const int b = blockIdx.x;
  const int j = threadIdx.x;  // 128
  if (j < 32) {
    float p = partials[(long)b * 32 + j];
    p += __shfl_xor(p, 1); p += __shfl_xor(p, 2); p += __shfl_xor(p, 4);
    p += __shfl_xor(p, 8); p += __shfl_xor(p, 16);
    if (j == 0) tsh = p;
  }
  __syncthreads();
  float tmean = tsh * (1.0f / 2048.0f);
  float v;
  if (j < 64) v = sinf(7.0f * tmean * (float)(j + 1));
  else        v = cosf(7.0f * tmean * (float)(j - 63));
  enh[(long)b * 2176 + 2048 + j] = f2bf(v);
}

// gate = softmax(enh @ Wg + bg) via MFMA. One wave = 16 rows x 16 experts.
__global__ __launch_bounds__(64)
void gate2_k(const u16* __restrict__ enh, const u16* __restrict__ Wgt,
             const float* __restrict__ bg, float* __restrict__ gate)
{
  const int lane = threadIdx.x & 63;
  const int g = lane >> 4, r15 = lane & 15;
  const long rowbase = (long)blockIdx.x * 16;

  const u16* arow = enh + (rowbase + r15) * 2176 + g * 8;
  const u16* brow = Wgt + (long)r15 * 2176 + g * 8;

  facc4 acc = (facc4){0.f, 0.f, 0.f, 0.f};
#pragma unroll 4
  for (int kt = 0; kt < 2176; kt += 64) {
    bfrag8 a0 = *(const bfrag8*)(arow + kt);
    bfrag8 b0 = *(const bfrag8*)(brow + kt);
    bfrag8 a1 = *(const bfrag8*)(arow + kt + 32);
    bfrag8 b1 = *(const bfrag8*)(brow + kt + 32);
    acc = __builtin_amdgcn_mfma_f32_16x16x32_bf16(a0, b0, acc, 0, 0, 0);
    acc = __builtin_amdgcn_mfma_f32_16x16x32_bf16(a1, b1, acc, 0, 0, 0);
  }

  const float bb = bg[r15];
#pragma unroll
  for (int r = 0; r < 4; ++r) {
    float v = acc[r] + bb;
    float mx = v;
    mx = fmaxf(mx, __shfl_xor(mx, 1)); mx = fmaxf(mx, __shfl_xor(mx, 2));
    mx = fmaxf(mx, __shfl_xor(mx, 4)); mx = fmaxf(mx, __shfl_xor(mx, 8));
    float ex = expf(v - mx);
    float sum = ex;
    sum += __shfl_xor(sum, 1); sum += __shfl_xor(sum, 2);
    sum += __shfl_xor(sum, 4); sum += __shfl_xor(sum, 8);
    gate[(rowbase + g * 4 + r) * 16 + r15] = ex / sum;
  }
}

// comb[b][k] = sum_e expw[b][e*128+k], 8 k's per thread
__global__ __launch_bounds__(256)
void combine_k(const u16* __restrict__ expw, u16* __restrict__ comb)
{
  const long i = ((long)blockIdx.x * 256 + threadIdx.x) * 8;
  const long b = i >> 7;
  const int k = (int)(i & 127);
  float s[8] = {0.f, 0.f, 0.f, 0.f, 0.f, 0.f, 0.f, 0.f};
#pragma unroll
  for (int e = 0; e < 16; ++e) {
    uint4 v = *(const uint4*)(expw + b * 2048 + e * 128 + k);
    const u16* vp = (const u16*)&v;
#pragma unroll
    for (int j = 0; j < 8; ++j) s[j] += bf2f(vp[j]);
  }
  u16 o[8];
#pragma unroll
  for (int j = 0; j < 8; ++j) o[j] = f2bf(s[j]);
  *(uint4*)(comb + i) = *(const uint4*)o;
}

extern "C" void kernel_launch(void* const* d_in, const int* in_sizes, int n_in,
                              void* d_out, int out_size, void* d_ws,
                              size_t ws_size, hipStream_t stream)
{
  const float* x    = (const float*)d_in[0];
  const float* W_in = (const float*)d_in[1];
  const float* b_in = (const float*)d_in[2];
  const float* Wg   = (const float*)d_in[3];
  const float* bg   = (const float*)d_in[4];
  const float* We   = (const float*)d_in[5];
  const float* be   = (const float*)d_in[6];
  const float* Wo   = (const float*)d_in[7];
  const float* bo   = (const float*)d_in[8];
  const float* Wh   = (const float*)d_in[9];
  const float* bh   = (const float*)d_in[10];
  const float* Wcls = (const float*)d_in[11];
  const float* bcls = (const float*)d_in[12];
  float* out = (float*)d_out;

  char* ws = (char*)d_ws;
  u16* enhb   = (u16*)(ws);                    // 35,651,584  [8192][2176]
  u16* bufF   = (u16*)(ws + 35651584);         // 33,554,432  Wt_in+xb -> expw/h1/h3
  u16* bufA   = (u16*)(ws + 69206016);         //  8,912,896  Wt_e -> Wt_cls
  u16* Wt_o   = (u16*)(ws + 78118912);         //    524,288  [2048][128]
  u16* bufW1  = (u16*)(ws + 78643200);         //  8,388,608  Wh0 -> Wh2
  u16* bufW2  = (u16*)(ws + 87031808);         //  8,388,608  Wh1
  u16* comb   = (u16*)(ws + 95420416);         //  2,097,152  [8192][128]
  float* partials = (float*)(ws + 97517568);   //  1,048,576
  float* gate     = (float*)(ws + 98566144);   //    524,288
  u16* Wt_in  = bufF;                          // [2048][1024], dead after proj
  u16* xb     = bufF + 2097152;                // [8192][1024] bf16, dead after proj
  u16* Wgt    = bufF;                          // [64][2176] bf16, after proj
  u16* Wt_e   = bufA;                          // [2048][2176], dead after expert
  u16* Wt_cls = bufA;                          // [1024][2048]

  hipFuncSetAttribute((const void*)gemm8<EP_PROJ, 8>,
                      hipFuncAttributeMaxDynamicSharedMemorySize, 131072);
  hipFuncSetAttribute((const void*)gemm8<EP_EXPERT, 8>,
                      hipFuncAttributeMaxDynamicSharedMemorySize, 131072);
  hipFuncSetAttribute((const void*)gemm8<EP_CTX, 8>,
                      hipFuncAttributeMaxDynamicSharedMemorySize, 131072);
  hipFuncSetAttribute((const void*)gemm8<EP_RELU, 8>,
                      hipFuncAttributeMaxDynamicSharedMemorySize, 131072);
  hipFuncSetAttribute((const void*)gemm8<EP_OUT, 4>,
                      hipFuncAttributeMaxDynamicSharedMemorySize, 98304);

  // ---- conversions needed before the first GEMMs
  f32_to_bf16_k<<<4096, 256, 0, stream>>>(x, xb);
  transpose_conv_k<<<dim3(32, 16, 1), 256, 0, stream>>>(W_in, Wt_in, 1024, 2048, 1024, 0, 0);
  transpose_conv_k<<<dim3(2, 34, 16), 256, 0, stream>>>(We, Wt_e, 2176, 128, 2176, 2176L * 128L, 128);
  transpose_conv_k<<<dim3(32, 2, 1), 256, 0, stream>>>(Wo, Wt_o, 128, 2048, 128, 0, 0);
  // Wh0 -> bufW1, Wh1 -> bufW2 (contiguous): one z=2 launch
  transpose_conv_k<<<dim3(32, 32, 2), 256, 0, stream>>>(Wh, bufW1, 2048, 2048, 2048, 2048L * 2048L, 2048);

  // 1) proj = x @ W_in + b_in -> enhb[:, :2048] + row partial sums
  gemm8<EP_PROJ, 8><<<dim3(8, 32), 512, 131072, stream>>>(
      xb, Wt_in, b_in, (void*)enhb, nullptr, partials, 1024, 1024, 1024, 2176, 2048);
  // 2) phasor bank -> enhb[:, 2048:]
  temporal_k<<<8192, 128, 0, stream>>>(partials, enhb);
  // Wt_in/xb dead -> transpose Wg into Wgt for the gate GEMM
  transpose_conv_k<<<dim3(1, 34, 1), 256, 0, stream>>>(Wg, Wgt, 2176, 16, 2176, 0, 0);
  // 3) softmax gate via MFMA
  gate2_k<<<512, 64, 0, stream>>>(enhb, Wgt, bg, gate);
  // 4) experts: relu(enh @ We + be) * gate
  gemm8<EP_EXPERT, 8><<<dim3(8, 32), 512, 131072, stream>>>(
      enhb, Wt_e, be, (void*)bufF, gate, nullptr, 2176, 2176, 2176, 2048, 2048);
  // Wt_e dead -> convert Wcls into bufA
  transpose_conv_k<<<dim3(16, 32, 1), 256, 0, stream>>>(Wcls, Wt_cls, 2048, 1000, 2048, 0, 0);
  // 5) combine experts
  combine_k<<<512, 256, 0, stream>>>(bufF, comb);
  // 6) context = comb @ Wo + bo, cols<20 doubled -> attended (enhb region)
  gemm8<EP_CTX, 8><<<dim3(8, 32), 512, 131072, stream>>>(
      comb, Wt_o, bo, (void*)enhb, nullptr, nullptr, 128, 128, 128, 2048, 2048);
  // 7) MLP: h1 -> bufF, h2 -> enhb, h3 -> bufF
  gemm8<EP_RELU, 8><<<dim3(8, 32), 512, 131072, stream>>>(
      enhb, bufW1, bh, (void*)bufF, nullptr, nullptr, 2048, 2048, 2048, 2048, 2048);
  transpose_conv_k<<<dim3(32, 32, 1), 256, 0, stream>>>(Wh + 2L * 2048L * 2048L, bufW1, 2048, 2048, 2048, 0, 0);
  gemm8<EP_RELU, 8><<<dim3(8, 32), 512, 131072, stream>>>(
      bufF, bufW2, bh + 2048, (void*)enhb, nullptr, nullptr, 2048, 2048, 2048, 2048, 2048);
  gemm8<EP_RELU, 8><<<dim3(8, 32), 512, 131072, stream>>>(
      enhb, bufW1, bh + 4096, (void*)bufF, nullptr, nullptr, 2048, 2048, 2048, 2048, 2048);
  // 8) logits: BM=128 variant, grid (4,64) = 256 blocks -> full CU utilization.
  gemm8<EP_OUT, 4><<<dim3(4, 64), 512, 98304, stream>>>(
      bufF, Wt_cls, bcls, (void*)out, nullptr, nullptr, 2048, 2048, 2048, 1000, 1000);
}